// Round 1
// baseline (320.553 us; speedup 1.0000x reference)
//
#include <hip/hip_runtime.h>
#include <math.h>

using u8  = unsigned char;
using u32 = unsigned int;
using u64 = unsigned long long;

#define MC 2048
#define NC 2048
#define DF 256
#define NFULL 50000
#define NBACK 30000
#define KCORR 4096
#define MAXPTS 256

// ---------------- workspace layout ----------------
constexpr size_t OFF_D    = 0;                               // 2048*2048 f32 = 16 MB
constexpr size_t OFF_GT   = (size_t)16 * 1024 * 1024;        // 2048*2048 u8 = 4 MB
constexpr size_t PN_STRIDE = 50048;
constexpr size_t OFF_PN   = OFF_GT + (size_t)4 * 1024 * 1024;        // 2*50048 f32
constexpr size_t OFF_NN   = OFF_PN + 2 * PN_STRIDE * 4;              // 4096 u64
constexpr size_t BM_WORDS = 1568;                                    // ceil(50000/32)+pad
constexpr size_t OFF_BM   = OFF_NN + 4096 * 8;                       // 2*1568 u32
constexpr size_t OFF_MASK = OFF_BM + 2 * BM_WORDS * 4;               // 4096 u8
constexpr size_t OFF_CAND = OFF_MASK + 4096;                         // 4096 u64
constexpr size_t OFF_ACC  = OFF_CAND + 4096 * 8;                     // 8 f32
constexpr size_t OFF_PART = OFF_ACC + 256;                           // 8*2048*4 f32

// ---------------- init ----------------
__global__ void k_init(u64* __restrict__ nn, u32* __restrict__ bm, float* __restrict__ acc) {
    int e = blockIdx.x * 256 + threadIdx.x;
    if (e < 4096) nn[e] = ~0ull;
    if (e < (int)(2 * BM_WORDS)) bm[e] = 0u;
    if (e < 8) acc[e] = 0.f;
}

// ---------------- |p|^2 ----------------
__global__ void k_pn(const float* __restrict__ pr, const float* __restrict__ ps, float* __restrict__ pn) {
    int e = blockIdx.x * 256 + threadIdx.x;
    if (e < NFULL) {
        float x = pr[e*3], y = pr[e*3+1], z = pr[e*3+2];
        pn[e] = x*x + y*y + z*z;
    } else if (e < 2*NFULL) {
        int j = e - NFULL;
        float x = ps[j*3], y = ps[j*3+1], z = ps[j*3+2];
        pn[PN_STRIDE + j] = x*x + y*y + z*z;
    }
}

// ---------------- back-index bitmaps ----------------
__global__ void k_bm(const int* __restrict__ rb, const int* __restrict__ sb, u32* __restrict__ bm) {
    int e = blockIdx.x * 256 + threadIdx.x;
    if (e < NBACK) {
        int v = rb[e];
        atomicOr(&bm[v >> 5], 1u << (v & 31));
    } else if (e < 2*NBACK) {
        int v = sb[e - NBACK];
        atomicOr(&bm[BM_WORDS + (v >> 5)], 1u << (v & 31));
    }
}

// ---------------- NN argmin ----------------
// grid: x = 8 i-blocks * 25 j-chunks, y = side. block 256.
__global__ __launch_bounds__(256) void k_nn(
        const float* __restrict__ fr, const float* __restrict__ fs,
        const float* __restrict__ cr, const float* __restrict__ cs,
        const float* __restrict__ pn, u64* __restrict__ nn) {
    const int side = blockIdx.y;
    const float* full = side ? fs : fr;
    const float* corr = side ? cs : cr;
    const float* pns  = pn + (side ? PN_STRIDE : 0);
    const int ib = blockIdx.x & 7, ch = blockIdx.x >> 3;
    const int i = ib * 256 + threadIdx.x;
    const float cx = corr[i*3], cy = corr[i*3+1], cz = corr[i*3+2];
    const float cn = cx*cx + cy*cy + cz*cz;
    const float ax = -2.f*cx, ay = -2.f*cy, az = -2.f*cz;

    __shared__ float4 s4[512];
    float bd = 3.4e38f;
    int   bj = 0;
    const int j0c = ch * 2000, j1c = j0c + 2000;
    for (int j0 = j0c; j0 < j1c; j0 += 512) {
        const int cnt = min(512, j1c - j0);
        __syncthreads();
        for (int e = threadIdx.x; e < cnt; e += 256) {
            int j = j0 + e;
            s4[e] = make_float4(full[j*3], full[j*3+1], full[j*3+2], pns[j]);
        }
        __syncthreads();
        #pragma unroll 4
        for (int jj = 0; jj < cnt; ++jj) {
            float4 p = s4[jj];
            float d = p.w + fmaf(ax, p.x, fmaf(ay, p.y, fmaf(az, p.z, cn)));
            if (d < bd) { bd = d; bj = j0 + jj; }
        }
    }
    u32 db = __float_as_uint(bd);
    db = (db & 0x80000000u) ? ~db : (db | 0x80000000u);
    atomicMin(&nn[side * 2048 + i], ((u64)db << 32) | (u32)bj);
}

// ---------------- masks + loss2 ----------------
__global__ void k_mask(const u64* __restrict__ nn, const u32* __restrict__ bm,
                       const float* __restrict__ spm, u8* __restrict__ mask,
                       float* __restrict__ acc) {
    int t = blockIdx.x * 256 + threadIdx.x;   // 0..4095
    int side = t >> 11;
    u32 j = (u32)(nn[t] & 0xFFFFFFFFull);
    u32 bit = (bm[side * BM_WORDS + (j >> 5)] >> (j & 31)) & 1u;
    mask[t] = (u8)bit;
    float c = fabsf((1.f - spm[t]) - (float)bit);
    for (int o = 32; o; o >>= 1) c += __shfl_xor(c, o);
    __shared__ float wsum[4];
    if ((threadIdx.x & 63) == 0) wsum[threadIdx.x >> 6] = c;
    __syncthreads();
    if (threadIdx.x == 0) atomicAdd(&acc[2], wsum[0] + wsum[1] + wsum[2] + wsum[3]);
}

// ---------------- scatter (last-wins) + count + top-k cap ----------------
__device__ __forceinline__ void bitonic4096(u64* keys, bool asc) {
    const int tid = threadIdx.x;
    for (int k = 2; k <= 4096; k <<= 1) {
        for (int j = k >> 1; j > 0; j >>= 1) {
            for (int i = tid; i < 4096; i += 1024) {
                int ij = i ^ j;
                if (ij > i) {
                    bool up = (((i & k) == 0) == asc);
                    u64 a = keys[i], b = keys[ij];
                    if ((a > b) == up) { keys[i] = b; keys[ij] = a; }
                }
            }
            __syncthreads();
        }
    }
}

__global__ __launch_bounds__(1024) void k_scatter(
        const int* __restrict__ gti, const float* __restrict__ gtv,
        const u8* __restrict__ mask, u8* __restrict__ gt, u64* __restrict__ cand) {
    __shared__ u64 keys[4096];
    __shared__ int s_cnt;
    const int t = threadIdx.x;
    if (t == 0) s_cnt = 0;
    for (int k = t; k < 4096; k += 1024) {
        int xi = gti[2*k], yi = gti[2*k+1];
        int cell = xi * 2048 + yi;
        keys[k] = ((u64)cell << 12) | (u32)k;
        if (mask[xi] && mask[2048 + yi]) gt[cell] = 1;
    }
    __syncthreads();
    bitonic4096(keys, true);   // (cell asc, k asc)
    for (int e = t; e < 4096; e += 1024) {
        u64 ke = keys[e];
        int cell = (int)(ke >> 12);
        bool win = (e == 4095) || ((int)(keys[e+1] >> 12) != cell);
        if (win) {
            int xi = cell >> 11, yi = cell & 2047;
            if (mask[xi] && mask[2048 + yi]) {
                int kk = (int)(ke & 0xFFF);
                u32 vb = __float_as_uint(gtv[kk]);   // overlaps >= 0 -> bits monotonic
                int idx = atomicAdd(&s_cnt, 1);
                cand[idx] = (1ull << 62) | ((u64)vb << 22) | (u32)(0x3FFFFF - cell);
            }
        }
    }
    __threadfence();
    __syncthreads();
    const int cnt = s_cnt;
    if (cnt > MAXPTS) {
        for (int e = t; e < 4096; e += 1024) keys[e] = (e < cnt) ? cand[e] : 0ull;
        __syncthreads();
        bitonic4096(keys, false);  // value desc, cell asc
        for (int e = t; e < 4096; e += 1024) {
            if (e >= MAXPTS && e < cnt) {
                int cell = 0x3FFFFF - (int)(keys[e] & 0x3FFFFF);
                gt[cell] = 0;
            }
        }
    }
}

// ---------------- f32 GEMM + laplace epilogue -> d matrix ----------------
__global__ __launch_bounds__(256) void k_gemm(
        const float* __restrict__ A, const float* __restrict__ B,
        const float* __restrict__ spm, float* __restrict__ Dm) {
    __shared__ float As[8][128];
    __shared__ float Bs[8][128];
    const int tx = threadIdx.x & 15, ty = threadIdx.x >> 4;
    const int i0 = blockIdx.y * 128, j0 = blockIdx.x * 128;
    const int lr = threadIdx.x >> 1, lc = (threadIdx.x & 1) * 4;
    float acc[8][8] = {};
    for (int kk = 0; kk < 256; kk += 8) {
        float4 a4 = *(const float4*)(A + (size_t)(i0 + lr) * 256 + kk + lc);
        float4 b4 = *(const float4*)(B + (size_t)(j0 + lr) * 256 + kk + lc);
        __syncthreads();
        As[lc+0][lr] = a4.x; As[lc+1][lr] = a4.y; As[lc+2][lr] = a4.z; As[lc+3][lr] = a4.w;
        Bs[lc+0][lr] = b4.x; Bs[lc+1][lr] = b4.y; Bs[lc+2][lr] = b4.z; Bs[lc+3][lr] = b4.w;
        __syncthreads();
        #pragma unroll
        for (int k = 0; k < 8; ++k) {
            float a[8], b[8];
            *(float4*)(a)   = *(const float4*)(&As[k][ty*8]);
            *(float4*)(a+4) = *(const float4*)(&As[k][ty*8+4]);
            *(float4*)(b)   = *(const float4*)(&Bs[k][tx*8]);
            *(float4*)(b+4) = *(const float4*)(&Bs[k][tx*8+4]);
            #pragma unroll
            for (int u = 0; u < 8; ++u)
                #pragma unroll
                for (int v = 0; v < 8; ++v)
                    acc[u][v] = fmaf(a[u], b[v], acc[u][v]);
        }
    }
    float vmi[8], vmj[8];
    #pragma unroll
    for (int u = 0; u < 8; ++u) vmi[u] = 1.f - spm[i0 + ty*8 + u];
    #pragma unroll
    for (int v = 0; v < 8; ++v) vmj[v] = 1.f - spm[2048 + j0 + tx*8 + v];
    #pragma unroll
    for (int u = 0; u < 8; ++u) {
        float outv[8];
        #pragma unroll
        for (int v = 0; v < 8; ++v) {
            float s  = acc[u][v];
            float fs = fmaxf(2.f - 2.f*s, 0.f);
            outv[v] = sqrtf(fs) * expf(0.5f * vmi[u] * vmj[v]);
        }
        float* dst = Dm + (size_t)(i0 + ty*8 + u) * 2048 + j0 + tx*8;
        *(float4*)(dst)   = *(float4*)(outv);
        *(float4*)(dst+4) = *(float4*)(outv+4);
    }
}

__device__ __forceinline__ void circle_terms(float d, bool g, float& lp, float& ln) {
    if (g) { float a = d - 0.1f; lp = a > 0.f ? 24.f*a*a : 0.f; ln = 0.f; }
    else   { float b = 1.4f - d; ln = b > 0.f ? 24.f*b*b : 0.f; lp = 0.f; }
}

__device__ __forceinline__ float softplus_(float x) {
    return fmaxf(x, 0.f) + log1pf(expf(-fabsf(x)));
}

// ---------------- row logsumexp pass ----------------
__global__ __launch_bounds__(256) void k_row(const float* __restrict__ Dm,
                                             const u8* __restrict__ gt,
                                             float* __restrict__ acc) {
    const int r = blockIdx.x, t = threadIdx.x;
    const float* dp = Dm + (size_t)r * 2048 + t * 8;
    float dv[8];
    *(float4*)(dv)   = *(const float4*)(dp);
    *(float4*)(dv+4) = *(const float4*)(dp + 4);
    u64 g8 = *(const u64*)(gt + (size_t)r * 2048 + t * 8);
    float lp[8], ln[8];
    #pragma unroll
    for (int e = 0; e < 8; ++e) {
        bool g = ((g8 >> (8*e)) & 0xFFull) != 0;
        circle_terms(dv[e], g, lp[e], ln[e]);
    }
    float mp = lp[0], mn = ln[0];
    #pragma unroll
    for (int e = 1; e < 8; ++e) { mp = fmaxf(mp, lp[e]); mn = fmaxf(mn, ln[e]); }
    for (int o = 32; o; o >>= 1) { mp = fmaxf(mp, __shfl_xor(mp, o)); mn = fmaxf(mn, __shfl_xor(mn, o)); }
    __shared__ float sm[2][4];
    int w = t >> 6;
    if ((t & 63) == 0) { sm[0][w] = mp; sm[1][w] = mn; }
    __syncthreads();
    mp = fmaxf(fmaxf(sm[0][0], sm[0][1]), fmaxf(sm[0][2], sm[0][3]));
    mn = fmaxf(fmaxf(sm[1][0], sm[1][1]), fmaxf(sm[1][2], sm[1][3]));
    float sp_ = 0.f, sn_ = 0.f;
    #pragma unroll
    for (int e = 0; e < 8; ++e) { sp_ += expf(lp[e] - mp); sn_ += expf(ln[e] - mn); }
    for (int o = 32; o; o >>= 1) { sp_ += __shfl_xor(sp_, o); sn_ += __shfl_xor(sn_, o); }
    __shared__ float ss[2][4];
    if ((t & 63) == 0) { ss[0][w] = sp_; ss[1][w] = sn_; }
    __syncthreads();
    if (t == 0) {
        float SP = ss[0][0] + ss[0][1] + ss[0][2] + ss[0][3];
        float SN = ss[1][0] + ss[1][1] + ss[1][2] + ss[1][3];
        float x = (mp + logf(SP)) + (mn + logf(SN));
        atomicAdd(&acc[0], softplus_(x) * (1.f / 24.f));
    }
}

// ---------------- col logsumexp: phase 1 (partials) ----------------
__global__ __launch_bounds__(256) void k_col1(const float* __restrict__ Dm,
                                              const u8* __restrict__ gt,
                                              float* __restrict__ part) {
    const int t = threadIdx.x;
    const int cl = t & 63, rq = t >> 6;
    const int c = blockIdx.x * 64 + cl;
    const int r0 = blockIdx.y * 256;
    float mp = -INFINITY, sp_ = 0.f, mn = -INFINITY, sn_ = 0.f;
    for (int r = r0 + rq; r < r0 + 256; r += 4) {
        float d = Dm[(size_t)r * 2048 + c];
        bool g = gt[(size_t)r * 2048 + c] != 0;
        float lp, ln;
        circle_terms(d, g, lp, ln);
        float nm = fmaxf(mp, lp); sp_ = sp_ * expf(mp - nm) + expf(lp - nm); mp = nm;
        nm = fmaxf(mn, ln); sn_ = sn_ * expf(mn - nm) + expf(ln - nm); mn = nm;
    }
    __shared__ float red[4][64][4];
    red[rq][cl][0] = mp; red[rq][cl][1] = sp_; red[rq][cl][2] = mn; red[rq][cl][3] = sn_;
    __syncthreads();
    if (rq == 0) {
        float M = mp, S = sp_, Mn = mn, Sn = sn_;
        #pragma unroll
        for (int q = 1; q < 4; ++q) {
            float m2 = red[q][cl][0], s2 = red[q][cl][1];
            float nm = fmaxf(M, m2);
            S = S * expf(M - nm) + s2 * expf(m2 - nm); M = nm;
            m2 = red[q][cl][2]; s2 = red[q][cl][3];
            nm = fmaxf(Mn, m2);
            Sn = Sn * expf(Mn - nm) + s2 * expf(m2 - nm); Mn = nm;
        }
        float* p = part + ((size_t)blockIdx.y * 2048 + c) * 4;
        p[0] = M; p[1] = S; p[2] = Mn; p[3] = Sn;
    }
}

// ---------------- col logsumexp: phase 2 (merge + loss) ----------------
__global__ void k_col2(const float* __restrict__ part, float* __restrict__ acc) {
    int c = blockIdx.x * 256 + threadIdx.x;   // 0..2047
    float M = -INFINITY, S = 0.f, Mn = -INFINITY, Sn = 0.f;
    for (int q = 0; q < 8; ++q) {
        const float* p = part + ((size_t)q * 2048 + c) * 4;
        float m2 = p[0], s2 = p[1];
        float nm = fmaxf(M, m2);
        S = S * expf(M - nm) + s2 * expf(m2 - nm); M = nm;
        m2 = p[2]; s2 = p[3];
        nm = fmaxf(Mn, m2);
        Sn = Sn * expf(Mn - nm) + s2 * expf(m2 - nm); Mn = nm;
    }
    float x = (M + logf(S)) + (Mn + logf(Sn));
    float l = softplus_(x) * (1.f / 24.f);
    for (int o = 32; o; o >>= 1) l += __shfl_xor(l, o);
    __shared__ float wsum[4];
    if ((threadIdx.x & 63) == 0) wsum[threadIdx.x >> 6] = l;
    __syncthreads();
    if (threadIdx.x == 0) atomicAdd(&acc[1], wsum[0] + wsum[1] + wsum[2] + wsum[3]);
}

// ---------------- finalize ----------------
__global__ void k_fin(const float* __restrict__ acc, float* __restrict__ out) {
    float l1 = (acc[0] + acc[1]) * (0.5f / 2048.f);
    float l2 = acc[2] * (1.f / 4096.f);
    out[0] = l1 + l2; out[1] = l1; out[2] = l2;
}

extern "C" void kernel_launch(void* const* d_in, const int* in_sizes, int n_in,
                              void* d_out, int out_size, void* d_ws, size_t ws_size,
                              hipStream_t stream) {
    (void)in_sizes; (void)n_in; (void)out_size; (void)ws_size;
    const float* ref_points = (const float*)d_in[0];
    const float* src_points = (const float*)d_in[1];
    const float* ref_c      = (const float*)d_in[2];
    const float* src_c      = (const float*)d_in[3];
    const float* ref_f      = (const float*)d_in[4];
    const float* src_f      = (const float*)d_in[5];
    const int*   gti        = (const int*)d_in[6];
    const float* gtv        = (const float*)d_in[7];
    const float* spm        = (const float*)d_in[8];
    const int*   rbi        = (const int*)d_in[9];
    const int*   sbi        = (const int*)d_in[10];

    char* ws = (char*)d_ws;
    float* Dm   = (float*)(ws + OFF_D);
    u8*    gt   = (u8*)   (ws + OFF_GT);
    float* pn   = (float*)(ws + OFF_PN);
    u64*   nn   = (u64*)  (ws + OFF_NN);
    u32*   bm   = (u32*)  (ws + OFF_BM);
    u8*    mask = (u8*)   (ws + OFF_MASK);
    u64*   cand = (u64*)  (ws + OFF_CAND);
    float* acc  = (float*)(ws + OFF_ACC);
    float* part = (float*)(ws + OFF_PART);

    hipMemsetAsync(gt, 0, (size_t)MC * NC, stream);
    k_init<<<16, 256, 0, stream>>>(nn, bm, acc);
    k_pn  <<<(2*NFULL + 255)/256, 256, 0, stream>>>(ref_points, src_points, pn);
    k_bm  <<<(2*NBACK + 255)/256, 256, 0, stream>>>(rbi, sbi, bm);
    k_nn  <<<dim3(200, 2), 256, 0, stream>>>(ref_points, src_points, ref_c, src_c, pn, nn);
    k_mask<<<16, 256, 0, stream>>>(nn, bm, spm, mask, acc);
    k_scatter<<<1, 1024, 0, stream>>>(gti, gtv, mask, gt, cand);
    k_gemm<<<dim3(16, 16), 256, 0, stream>>>(ref_f, src_f, spm, Dm);
    k_row <<<2048, 256, 0, stream>>>(Dm, gt, acc);
    k_col1<<<dim3(32, 8), 256, 0, stream>>>(Dm, gt, part);
    k_col2<<<8, 256, 0, stream>>>(part, acc);
    k_fin <<<1, 1, 0, stream>>>(acc, (float*)d_out);
}

// Round 2
// 241.605 us; speedup vs baseline: 1.3268x; 1.3268x over previous
//
#include <hip/hip_runtime.h>
#include <math.h>

using u8  = unsigned char;
using u32 = unsigned int;
using u64 = unsigned long long;

#define MC 2048
#define NC 2048
#define DF 256
#define NFULL 50000
#define NBACK 30000
#define KCORR 4096
#define MAXPTS 256

// ---------------- workspace layout ----------------
constexpr size_t OFF_D    = 0;                               // 2048*2048 f32 = 16 MB
constexpr size_t OFF_GT   = (size_t)16 * 1024 * 1024;        // 2048*2048 u8 = 4 MB
constexpr size_t PN_STRIDE = 50048;
constexpr size_t OFF_PN   = OFF_GT + (size_t)4 * 1024 * 1024;        // 2*50048 f32
constexpr size_t OFF_NN   = OFF_PN + 2 * PN_STRIDE * 4;              // 4096 u64
constexpr size_t BM_WORDS = 1568;                                    // ceil(50000/32)+pad
constexpr size_t OFF_BM   = OFF_NN + 4096 * 8;                       // 2*1568 u32
constexpr size_t OFF_MASK = OFF_BM + 2 * BM_WORDS * 4;               // 4096 u8
constexpr size_t OFF_CAND = OFF_MASK + 4096;                         // 4096 u64
constexpr size_t OFF_ACC  = OFF_CAND + 4096 * 8;                     // 8 f32
constexpr size_t OFF_CNT  = OFF_ACC + 256;                           // 1 u32 (+pad)
constexpr size_t OFF_PART = OFF_CNT + 256;                           // 8*2048*4 f32 = 256 KB
constexpr size_t OFF_HASH = OFF_PART + (size_t)8 * 2048 * 4 * 4;     // 8192 u64 = 64 KB

// ---------------- init ----------------
__global__ void k_init(u64* __restrict__ nn, u32* __restrict__ bm, float* __restrict__ acc,
                       u64* __restrict__ hash, u32* __restrict__ cnt) {
    int e = blockIdx.x * 256 + threadIdx.x;   // 0..8191
    if (e < 4096) nn[e] = ~0ull;
    if (e < (int)(2 * BM_WORDS)) bm[e] = 0u;
    if (e < 8) acc[e] = 0.f;
    if (e == 0) *cnt = 0u;
    hash[e] = 0ull;
}

// ---------------- |p|^2 ----------------
__global__ void k_pn(const float* __restrict__ pr, const float* __restrict__ ps, float* __restrict__ pn) {
    int e = blockIdx.x * 256 + threadIdx.x;
    if (e < NFULL) {
        float x = pr[e*3], y = pr[e*3+1], z = pr[e*3+2];
        pn[e] = x*x + y*y + z*z;
    } else if (e < 2*NFULL) {
        int j = e - NFULL;
        float x = ps[j*3], y = ps[j*3+1], z = ps[j*3+2];
        pn[PN_STRIDE + j] = x*x + y*y + z*z;
    }
}

// ---------------- back-index bitmaps ----------------
__global__ void k_bm(const int* __restrict__ rb, const int* __restrict__ sb, u32* __restrict__ bm) {
    int e = blockIdx.x * 256 + threadIdx.x;
    if (e < NBACK) {
        int v = rb[e];
        atomicOr(&bm[v >> 5], 1u << (v & 31));
    } else if (e < 2*NBACK) {
        int v = sb[e - NBACK];
        atomicOr(&bm[BM_WORDS + (v >> 5)], 1u << (v & 31));
    }
}

// ---------------- NN argmin ----------------
// grid: x = 8 i-blocks * 25 j-chunks, y = side. block 256.
__global__ __launch_bounds__(256) void k_nn(
        const float* __restrict__ fr, const float* __restrict__ fs,
        const float* __restrict__ cr, const float* __restrict__ cs,
        const float* __restrict__ pn, u64* __restrict__ nn) {
    const int side = blockIdx.y;
    const float* full = side ? fs : fr;
    const float* corr = side ? cs : cr;
    const float* pns  = pn + (side ? PN_STRIDE : 0);
    const int ib = blockIdx.x & 7, ch = blockIdx.x >> 3;
    const int i = ib * 256 + threadIdx.x;
    const float cx = corr[i*3], cy = corr[i*3+1], cz = corr[i*3+2];
    const float cn = cx*cx + cy*cy + cz*cz;
    const float ax = -2.f*cx, ay = -2.f*cy, az = -2.f*cz;

    __shared__ float4 s4[512];
    float bd = 3.4e38f;
    int   bj = 0;
    const int j0c = ch * 2000, j1c = j0c + 2000;
    for (int j0 = j0c; j0 < j1c; j0 += 512) {
        const int cnt = min(512, j1c - j0);
        __syncthreads();
        for (int e = threadIdx.x; e < cnt; e += 256) {
            int j = j0 + e;
            s4[e] = make_float4(full[j*3], full[j*3+1], full[j*3+2], pns[j]);
        }
        __syncthreads();
        #pragma unroll 4
        for (int jj = 0; jj < cnt; ++jj) {
            float4 p = s4[jj];
            float d = p.w + fmaf(ax, p.x, fmaf(ay, p.y, fmaf(az, p.z, cn)));
            if (d < bd) { bd = d; bj = j0 + jj; }
        }
    }
    u32 db = __float_as_uint(bd);
    db = (db & 0x80000000u) ? ~db : (db | 0x80000000u);
    atomicMin(&nn[side * 2048 + i], ((u64)db << 32) | (u32)bj);
}

// ---------------- masks + loss2 ----------------
__global__ void k_mask(const u64* __restrict__ nn, const u32* __restrict__ bm,
                       const float* __restrict__ spm, u8* __restrict__ mask,
                       float* __restrict__ acc) {
    int t = blockIdx.x * 256 + threadIdx.x;   // 0..4095
    int side = t >> 11;
    u32 j = (u32)(nn[t] & 0xFFFFFFFFull);
    u32 bit = (bm[side * BM_WORDS + (j >> 5)] >> (j & 31)) & 1u;
    mask[t] = (u8)bit;
    float c = fabsf((1.f - spm[t]) - (float)bit);
    for (int o = 32; o; o >>= 1) c += __shfl_xor(c, o);
    __shared__ float wsum[4];
    if ((threadIdx.x & 63) == 0) wsum[threadIdx.x >> 6] = c;
    __syncthreads();
    if (threadIdx.x == 0) atomicAdd(&acc[2], wsum[0] + wsum[1] + wsum[2] + wsum[3]);
}

// ---------------- scatter phase 1: gt set + last-wins dedup via hash ----------------
// hash slot: ((cell+1) << 12) | k ;  atomicMax gives max k per cell == last-wins.
__global__ void k_scat1(const int* __restrict__ gti, const u8* __restrict__ mask,
                        u8* __restrict__ gt, u64* __restrict__ hash) {
    int k = blockIdx.x * 256 + threadIdx.x;   // 0..4095
    int xi = gti[2*k], yi = gti[2*k+1];
    u32 cell = (u32)(xi * 2048 + yi);
    if (mask[xi] && mask[2048 + yi]) gt[cell] = 1;
    u64 val = ((u64)(cell + 1) << 12) | (u32)k;
    u32 h = (cell * 2654435761u) >> 19;       // 13-bit hash -> 8192 slots
    while (true) {
        u64 cur = hash[h];
        if ((cur >> 12) == (u64)(cell + 1)) { atomicMax(&hash[h], val); return; }
        if (cur == 0ull) {
            u64 prev = atomicCAS(&hash[h], 0ull, val);
            if (prev == 0ull) return;
            if ((prev >> 12) == (u64)(cell + 1)) { atomicMax(&hash[h], val); return; }
        }
        h = (h + 1) & 8191;
    }
}

// ---------------- scatter phase 2: collect masked candidates ----------------
// key = (value_bits << 22) | (0x3FFFFF - cell)  -> sorts (value desc, cell asc)
__global__ void k_scat2(const u64* __restrict__ hash, const float* __restrict__ gtv,
                        const u8* __restrict__ mask, u64* __restrict__ cand,
                        u32* __restrict__ cnt) {
    int e = blockIdx.x * 256 + threadIdx.x;   // 0..8191
    u64 s = hash[e];
    if (s == 0ull) return;
    u32 cell = (u32)(s >> 12) - 1u;
    int xi = cell >> 11, yi = cell & 2047;
    if (!(mask[xi] && mask[2048 + yi])) return;
    u32 k = (u32)(s & 0xFFFull);
    u32 vb = __float_as_uint(gtv[k]);         // overlaps >= 0 -> bits monotonic
    u32 idx = atomicAdd(cnt, 1u);
    cand[idx] = ((u64)vb << 22) | (u32)(0x3FFFFF - cell);
}

// ---------------- scatter phase 3: top-256 cap via O(n^2) rank ----------------
__global__ __launch_bounds__(1024) void k_top(const u64* __restrict__ cand,
                                              const u32* __restrict__ cnt,
                                              u8* __restrict__ gt) {
    __shared__ u64 keys[4096];
    const int n = (int)*cnt;
    if (n <= MAXPTS) return;
    const int t = threadIdx.x;
    for (int e = t; e < n; e += 1024) keys[e] = cand[e];
    __syncthreads();
    for (int c = t; c < n; c += 1024) {
        u64 me = keys[c];
        int rank = 0;
        for (int j = 0; j < n; ++j) rank += (keys[j] > me);
        if (rank >= MAXPTS) {
            u32 cell = 0x3FFFFFu - (u32)(me & 0x3FFFFFull);
            gt[cell] = 0;
        }
    }
}

// ---------------- f32 GEMM + laplace epilogue -> d matrix ----------------
__global__ __launch_bounds__(256) void k_gemm(
        const float* __restrict__ A, const float* __restrict__ B,
        const float* __restrict__ spm, float* __restrict__ Dm) {
    __shared__ float As[8][128];
    __shared__ float Bs[8][128];
    const int tx = threadIdx.x & 15, ty = threadIdx.x >> 4;
    const int i0 = blockIdx.y * 128, j0 = blockIdx.x * 128;
    const int lr = threadIdx.x >> 1, lc = (threadIdx.x & 1) * 4;
    float acc[8][8] = {};
    for (int kk = 0; kk < 256; kk += 8) {
        float4 a4 = *(const float4*)(A + (size_t)(i0 + lr) * 256 + kk + lc);
        float4 b4 = *(const float4*)(B + (size_t)(j0 + lr) * 256 + kk + lc);
        __syncthreads();
        As[lc+0][lr] = a4.x; As[lc+1][lr] = a4.y; As[lc+2][lr] = a4.z; As[lc+3][lr] = a4.w;
        Bs[lc+0][lr] = b4.x; Bs[lc+1][lr] = b4.y; Bs[lc+2][lr] = b4.z; Bs[lc+3][lr] = b4.w;
        __syncthreads();
        #pragma unroll
        for (int k = 0; k < 8; ++k) {
            float a[8], b[8];
            *(float4*)(a)   = *(const float4*)(&As[k][ty*8]);
            *(float4*)(a+4) = *(const float4*)(&As[k][ty*8+4]);
            *(float4*)(b)   = *(const float4*)(&Bs[k][tx*8]);
            *(float4*)(b+4) = *(const float4*)(&Bs[k][tx*8+4]);
            #pragma unroll
            for (int u = 0; u < 8; ++u)
                #pragma unroll
                for (int v = 0; v < 8; ++v)
                    acc[u][v] = fmaf(a[u], b[v], acc[u][v]);
        }
    }
    float vmi[8], vmj[8];
    #pragma unroll
    for (int u = 0; u < 8; ++u) vmi[u] = 1.f - spm[i0 + ty*8 + u];
    #pragma unroll
    for (int v = 0; v < 8; ++v) vmj[v] = 1.f - spm[2048 + j0 + tx*8 + v];
    #pragma unroll
    for (int u = 0; u < 8; ++u) {
        float outv[8];
        #pragma unroll
        for (int v = 0; v < 8; ++v) {
            float s  = acc[u][v];
            float fs = fmaxf(2.f - 2.f*s, 0.f);
            outv[v] = sqrtf(fs) * expf(0.5f * vmi[u] * vmj[v]);
        }
        float* dst = Dm + (size_t)(i0 + ty*8 + u) * 2048 + j0 + tx*8;
        *(float4*)(dst)   = *(float4*)(outv);
        *(float4*)(dst+4) = *(float4*)(outv+4);
    }
}

__device__ __forceinline__ void circle_terms(float d, bool g, float& lp, float& ln) {
    if (g) { float a = d - 0.1f; lp = a > 0.f ? 24.f*a*a : 0.f; ln = 0.f; }
    else   { float b = 1.4f - d; ln = b > 0.f ? 24.f*b*b : 0.f; lp = 0.f; }
}

__device__ __forceinline__ float softplus_(float x) {
    return fmaxf(x, 0.f) + log1pf(expf(-fabsf(x)));
}

// ---------------- row logsumexp pass ----------------
__global__ __launch_bounds__(256) void k_row(const float* __restrict__ Dm,
                                             const u8* __restrict__ gt,
                                             float* __restrict__ acc) {
    const int r = blockIdx.x, t = threadIdx.x;
    const float* dp = Dm + (size_t)r * 2048 + t * 8;
    float dv[8];
    *(float4*)(dv)   = *(const float4*)(dp);
    *(float4*)(dv+4) = *(const float4*)(dp + 4);
    u64 g8 = *(const u64*)(gt + (size_t)r * 2048 + t * 8);
    float lp[8], ln[8];
    #pragma unroll
    for (int e = 0; e < 8; ++e) {
        bool g = ((g8 >> (8*e)) & 0xFFull) != 0;
        circle_terms(dv[e], g, lp[e], ln[e]);
    }
    float mp = lp[0], mn = ln[0];
    #pragma unroll
    for (int e = 1; e < 8; ++e) { mp = fmaxf(mp, lp[e]); mn = fmaxf(mn, ln[e]); }
    for (int o = 32; o; o >>= 1) { mp = fmaxf(mp, __shfl_xor(mp, o)); mn = fmaxf(mn, __shfl_xor(mn, o)); }
    __shared__ float sm[2][4];
    int w = t >> 6;
    if ((t & 63) == 0) { sm[0][w] = mp; sm[1][w] = mn; }
    __syncthreads();
    mp = fmaxf(fmaxf(sm[0][0], sm[0][1]), fmaxf(sm[0][2], sm[0][3]));
    mn = fmaxf(fmaxf(sm[1][0], sm[1][1]), fmaxf(sm[1][2], sm[1][3]));
    float sp_ = 0.f, sn_ = 0.f;
    #pragma unroll
    for (int e = 0; e < 8; ++e) { sp_ += expf(lp[e] - mp); sn_ += expf(ln[e] - mn); }
    for (int o = 32; o; o >>= 1) { sp_ += __shfl_xor(sp_, o); sn_ += __shfl_xor(sn_, o); }
    __shared__ float ss[2][4];
    if ((t & 63) == 0) { ss[0][w] = sp_; ss[1][w] = sn_; }
    __syncthreads();
    if (t == 0) {
        float SP = ss[0][0] + ss[0][1] + ss[0][2] + ss[0][3];
        float SN = ss[1][0] + ss[1][1] + ss[1][2] + ss[1][3];
        float x = (mp + logf(SP)) + (mn + logf(SN));
        atomicAdd(&acc[0], softplus_(x) * (1.f / 24.f));
    }
}

// ---------------- col logsumexp: phase 1 (partials) ----------------
__global__ __launch_bounds__(256) void k_col1(const float* __restrict__ Dm,
                                              const u8* __restrict__ gt,
                                              float* __restrict__ part) {
    const int t = threadIdx.x;
    const int cl = t & 63, rq = t >> 6;
    const int c = blockIdx.x * 64 + cl;
    const int r0 = blockIdx.y * 256;
    float mp = -INFINITY, sp_ = 0.f, mn = -INFINITY, sn_ = 0.f;
    for (int r = r0 + rq; r < r0 + 256; r += 4) {
        float d = Dm[(size_t)r * 2048 + c];
        bool g = gt[(size_t)r * 2048 + c] != 0;
        float lp, ln;
        circle_terms(d, g, lp, ln);
        float nm = fmaxf(mp, lp); sp_ = sp_ * expf(mp - nm) + expf(lp - nm); mp = nm;
        nm = fmaxf(mn, ln); sn_ = sn_ * expf(mn - nm) + expf(ln - nm); mn = nm;
    }
    __shared__ float red[4][64][4];
    red[rq][cl][0] = mp; red[rq][cl][1] = sp_; red[rq][cl][2] = mn; red[rq][cl][3] = sn_;
    __syncthreads();
    if (rq == 0) {
        float M = mp, S = sp_, Mn = mn, Sn = sn_;
        #pragma unroll
        for (int q = 1; q < 4; ++q) {
            float m2 = red[q][cl][0], s2 = red[q][cl][1];
            float nm = fmaxf(M, m2);
            S = S * expf(M - nm) + s2 * expf(m2 - nm); M = nm;
            m2 = red[q][cl][2]; s2 = red[q][cl][3];
            nm = fmaxf(Mn, m2);
            Sn = Sn * expf(Mn - nm) + s2 * expf(m2 - nm); Mn = nm;
        }
        float* p = part + ((size_t)blockIdx.y * 2048 + c) * 4;
        p[0] = M; p[1] = S; p[2] = Mn; p[3] = Sn;
    }
}

// ---------------- col logsumexp: phase 2 (merge + loss) ----------------
__global__ void k_col2(const float* __restrict__ part, float* __restrict__ acc) {
    int c = blockIdx.x * 256 + threadIdx.x;   // 0..2047
    float M = -INFINITY, S = 0.f, Mn = -INFINITY, Sn = 0.f;
    for (int q = 0; q < 8; ++q) {
        const float* p = part + ((size_t)q * 2048 + c) * 4;
        float m2 = p[0], s2 = p[1];
        float nm = fmaxf(M, m2);
        S = S * expf(M - nm) + s2 * expf(m2 - nm); M = nm;
        m2 = p[2]; s2 = p[3];
        nm = fmaxf(Mn, m2);
        Sn = Sn * expf(Mn - nm) + s2 * expf(m2 - nm); Mn = nm;
    }
    float x = (M + logf(S)) + (Mn + logf(Sn));
    float l = softplus_(x) * (1.f / 24.f);
    for (int o = 32; o; o >>= 1) l += __shfl_xor(l, o);
    __shared__ float wsum[4];
    if ((threadIdx.x & 63) == 0) wsum[threadIdx.x >> 6] = l;
    __syncthreads();
    if (threadIdx.x == 0) atomicAdd(&acc[1], wsum[0] + wsum[1] + wsum[2] + wsum[3]);
}

// ---------------- finalize ----------------
__global__ void k_fin(const float* __restrict__ acc, float* __restrict__ out) {
    float l1 = (acc[0] + acc[1]) * (0.5f / 2048.f);
    float l2 = acc[2] * (1.f / 4096.f);
    out[0] = l1 + l2; out[1] = l1; out[2] = l2;
}

extern "C" void kernel_launch(void* const* d_in, const int* in_sizes, int n_in,
                              void* d_out, int out_size, void* d_ws, size_t ws_size,
                              hipStream_t stream) {
    (void)in_sizes; (void)n_in; (void)out_size; (void)ws_size;
    const float* ref_points = (const float*)d_in[0];
    const float* src_points = (const float*)d_in[1];
    const float* ref_c      = (const float*)d_in[2];
    const float* src_c      = (const float*)d_in[3];
    const float* ref_f      = (const float*)d_in[4];
    const float* src_f      = (const float*)d_in[5];
    const int*   gti        = (const int*)d_in[6];
    const float* gtv        = (const float*)d_in[7];
    const float* spm        = (const float*)d_in[8];
    const int*   rbi        = (const int*)d_in[9];
    const int*   sbi        = (const int*)d_in[10];

    char* ws = (char*)d_ws;
    float* Dm   = (float*)(ws + OFF_D);
    u8*    gt   = (u8*)   (ws + OFF_GT);
    float* pn   = (float*)(ws + OFF_PN);
    u64*   nn   = (u64*)  (ws + OFF_NN);
    u32*   bm   = (u32*)  (ws + OFF_BM);
    u8*    mask = (u8*)   (ws + OFF_MASK);
    u64*   cand = (u64*)  (ws + OFF_CAND);
    float* acc  = (float*)(ws + OFF_ACC);
    u32*   cnt  = (u32*)  (ws + OFF_CNT);
    float* part = (float*)(ws + OFF_PART);
    u64*   hash = (u64*)  (ws + OFF_HASH);

    hipMemsetAsync(gt, 0, (size_t)MC * NC, stream);
    k_init<<<32, 256, 0, stream>>>(nn, bm, acc, hash, cnt);
    k_pn  <<<(2*NFULL + 255)/256, 256, 0, stream>>>(ref_points, src_points, pn);
    k_bm  <<<(2*NBACK + 255)/256, 256, 0, stream>>>(rbi, sbi, bm);
    k_nn  <<<dim3(200, 2), 256, 0, stream>>>(ref_points, src_points, ref_c, src_c, pn, nn);
    k_mask<<<16, 256, 0, stream>>>(nn, bm, spm, mask, acc);
    k_scat1<<<16, 256, 0, stream>>>(gti, mask, gt, hash);
    k_scat2<<<32, 256, 0, stream>>>(hash, gtv, mask, cand, cnt);
    k_top <<<1, 1024, 0, stream>>>(cand, cnt, gt);
    k_gemm<<<dim3(16, 16), 256, 0, stream>>>(ref_f, src_f, spm, Dm);
    k_row <<<2048, 256, 0, stream>>>(Dm, gt, acc);
    k_col1<<<dim3(32, 8), 256, 0, stream>>>(Dm, gt, part);
    k_col2<<<8, 256, 0, stream>>>(part, acc);
    k_fin <<<1, 1, 0, stream>>>(acc, (float*)d_out);
}

// Round 3
// 199.912 us; speedup vs baseline: 1.6035x; 1.2086x over previous
//
#include <hip/hip_runtime.h>
#include <math.h>

using u8  = unsigned char;
using u32 = unsigned int;
using u64 = unsigned long long;

#define MC 2048
#define NC 2048
#define DF 256
#define NFULL 50000
#define NBACK 30000
#define KCORR 4096
#define MAXPTS 256
#define NN_CHUNK 391   // 128 chunks * 391 = 50048 >= 50000

// ---------------- workspace layout ----------------
constexpr size_t OFF_D    = 0;                               // 2048*2048 f32 = 16 MB
constexpr size_t OFF_GT   = (size_t)16 * 1024 * 1024;        // 2048*2048 u8 = 4 MB
constexpr size_t OFF_NN   = OFF_GT + (size_t)4 * 1024 * 1024;        // 4096 u64
constexpr size_t BM_WORDS = 1568;                                    // ceil(50000/32)+pad
constexpr size_t OFF_BM   = OFF_NN + 4096 * 8;                       // 2*1568 u32
constexpr size_t OFF_MASK = OFF_BM + 2 * BM_WORDS * 4;               // 4096 u8
constexpr size_t OFF_CAND = OFF_MASK + 4096;                         // 4096 u64
constexpr size_t OFF_ACC  = OFF_CAND + 4096 * 8;                     // 8 f32
constexpr size_t OFF_CNT  = OFF_ACC + 256;                           // 1 u32 (+pad)
constexpr size_t OFF_PART = OFF_CNT + 256;                           // 8*2048*4 f32 = 256 KB
constexpr size_t OFF_HASH = OFF_PART + (size_t)8 * 2048 * 4 * 4;     // 8192 u64 = 64 KB

// ---------------- init ----------------
__global__ void k_init(u64* __restrict__ nn, u32* __restrict__ bm, float* __restrict__ acc,
                       u64* __restrict__ hash, u32* __restrict__ cnt) {
    int e = blockIdx.x * 256 + threadIdx.x;   // 0..8191
    if (e < 4096) nn[e] = ~0ull;
    if (e < (int)(2 * BM_WORDS)) bm[e] = 0u;
    if (e < 8) acc[e] = 0.f;
    if (e == 0) *cnt = 0u;
    hash[e] = 0ull;
}

// ---------------- back-index bitmaps ----------------
__global__ void k_bm(const int* __restrict__ rb, const int* __restrict__ sb, u32* __restrict__ bm) {
    int e = blockIdx.x * 256 + threadIdx.x;
    if (e < NBACK) {
        int v = rb[e];
        atomicOr(&bm[v >> 5], 1u << (v & 31));
    } else if (e < 2*NBACK) {
        int v = sb[e - NBACK];
        atomicOr(&bm[BM_WORDS + (v >> 5)], 1u << (v & 31));
    }
}

// ---------------- NN argmin ----------------
// grid: x = (2 i-blocks) | (128 chunks << 1), y = side. block 256.
// Each thread owns 4 corr points; chunk staged once into LDS (pw computed on
// the fly); comparison chain omits the per-point constant cn (argmin-invariant),
// cn re-added before the packed atomicMin so cross-block merge is consistent.
__global__ __launch_bounds__(256) void k_nn(
        const float* __restrict__ fr, const float* __restrict__ fs,
        const float* __restrict__ cr, const float* __restrict__ cs,
        u64* __restrict__ nn) {
    const int side = blockIdx.y;
    const float* full = side ? fs : fr;
    const float* corr = side ? cs : cr;
    const int ib = blockIdx.x & 1, ch = blockIdx.x >> 1;
    const int t = threadIdx.x;

    __shared__ float4 s4[NN_CHUNK];
    const int j0 = ch * NN_CHUNK;
    for (int e = t; e < NN_CHUNK; e += 256) {
        int j = j0 + e;
        float4 v;
        if (j < NFULL) {
            float x = full[j*3], y = full[j*3+1], z = full[j*3+2];
            v = make_float4(x, y, z, x*x + y*y + z*z);
        } else {
            v = make_float4(0.f, 0.f, 0.f, 3.0e38f);   // sentinel: never wins
        }
        s4[e] = v;
    }

    float ax[4], ay[4], az[4], bd[4];
    u32 bj[4];
    #pragma unroll
    for (int q = 0; q < 4; ++q) {
        int i = ib * 1024 + q * 256 + t;
        float cx = corr[i*3], cy = corr[i*3+1], cz = corr[i*3+2];
        ax[q] = -2.f*cx; ay[q] = -2.f*cy; az[q] = -2.f*cz;
        bd[q] = 3.4e38f; bj[q] = 0u;
    }
    __syncthreads();

    #pragma unroll 4
    for (int jj = 0; jj < NN_CHUNK; ++jj) {
        float4 p = s4[jj];
        #pragma unroll
        for (int q = 0; q < 4; ++q) {
            float d = fmaf(ax[q], p.x, fmaf(ay[q], p.y, fmaf(az[q], p.z, p.w)));
            if (d < bd[q]) { bd[q] = d; bj[q] = (u32)(j0 + jj); }
        }
    }

    #pragma unroll
    for (int q = 0; q < 4; ++q) {
        int i = ib * 1024 + q * 256 + t;
        float cn = 0.25f * fmaf(ax[q], ax[q], fmaf(ay[q], ay[q], az[q]*az[q]));
        float bf = bd[q] + cn;
        u32 db = __float_as_uint(bf);
        db = (db & 0x80000000u) ? ~db : (db | 0x80000000u);
        atomicMin(&nn[side * 2048 + i], ((u64)db << 32) | bj[q]);
    }
}

// ---------------- masks + loss2 ----------------
__global__ void k_mask(const u64* __restrict__ nn, const u32* __restrict__ bm,
                       const float* __restrict__ spm, u8* __restrict__ mask,
                       float* __restrict__ acc) {
    int t = blockIdx.x * 256 + threadIdx.x;   // 0..4095
    int side = t >> 11;
    u32 j = (u32)(nn[t] & 0xFFFFFFFFull);
    u32 bit = (bm[side * BM_WORDS + (j >> 5)] >> (j & 31)) & 1u;
    mask[t] = (u8)bit;
    float c = fabsf((1.f - spm[t]) - (float)bit);
    for (int o = 32; o; o >>= 1) c += __shfl_xor(c, o);
    __shared__ float wsum[4];
    if ((threadIdx.x & 63) == 0) wsum[threadIdx.x >> 6] = c;
    __syncthreads();
    if (threadIdx.x == 0) atomicAdd(&acc[2], wsum[0] + wsum[1] + wsum[2] + wsum[3]);
}

// ---------------- scatter phase 1: gt set + last-wins dedup via hash ----------------
// hash slot: ((cell+1) << 12) | k ;  atomicMax gives max k per cell == last-wins.
__global__ void k_scat1(const int* __restrict__ gti, const u8* __restrict__ mask,
                        u8* __restrict__ gt, u64* __restrict__ hash) {
    int k = blockIdx.x * 256 + threadIdx.x;   // 0..4095
    int xi = gti[2*k], yi = gti[2*k+1];
    u32 cell = (u32)(xi * 2048 + yi);
    if (mask[xi] && mask[2048 + yi]) gt[cell] = 1;
    u64 val = ((u64)(cell + 1) << 12) | (u32)k;
    u32 h = (cell * 2654435761u) >> 19;       // 13-bit hash -> 8192 slots
    while (true) {
        u64 cur = hash[h];
        if ((cur >> 12) == (u64)(cell + 1)) { atomicMax(&hash[h], val); return; }
        if (cur == 0ull) {
            u64 prev = atomicCAS(&hash[h], 0ull, val);
            if (prev == 0ull) return;
            if ((prev >> 12) == (u64)(cell + 1)) { atomicMax(&hash[h], val); return; }
        }
        h = (h + 1) & 8191;
    }
}

// ---------------- scatter phase 2: collect masked candidates ----------------
// key = (value_bits << 22) | (0x3FFFFF - cell)  -> sorts (value desc, cell asc)
__global__ void k_scat2(const u64* __restrict__ hash, const float* __restrict__ gtv,
                        const u8* __restrict__ mask, u64* __restrict__ cand,
                        u32* __restrict__ cnt) {
    int e = blockIdx.x * 256 + threadIdx.x;   // 0..8191
    u64 s = hash[e];
    if (s == 0ull) return;
    u32 cell = (u32)(s >> 12) - 1u;
    int xi = cell >> 11, yi = cell & 2047;
    if (!(mask[xi] && mask[2048 + yi])) return;
    u32 k = (u32)(s & 0xFFFull);
    u32 vb = __float_as_uint(gtv[k]);         // overlaps >= 0 -> bits monotonic
    u32 idx = atomicAdd(cnt, 1u);
    cand[idx] = ((u64)vb << 22) | (u32)(0x3FFFFF - cell);
}

// ---------------- scatter phase 3: top-256 cap via O(n^2) rank ----------------
__global__ __launch_bounds__(1024) void k_top(const u64* __restrict__ cand,
                                              const u32* __restrict__ cnt,
                                              u8* __restrict__ gt) {
    __shared__ u64 keys[4096];
    const int n = (int)*cnt;
    if (n <= MAXPTS) return;
    const int t = threadIdx.x;
    for (int e = t; e < n; e += 1024) keys[e] = cand[e];
    __syncthreads();
    for (int c = t; c < n; c += 1024) {
        u64 me = keys[c];
        int rank = 0;
        for (int j = 0; j < n; ++j) rank += (keys[j] > me);
        if (rank >= MAXPTS) {
            u32 cell = 0x3FFFFFu - (u32)(me & 0x3FFFFFull);
            gt[cell] = 0;
        }
    }
}

// ---------------- f32 GEMM + laplace epilogue -> d matrix ----------------
__global__ __launch_bounds__(256) void k_gemm(
        const float* __restrict__ A, const float* __restrict__ B,
        const float* __restrict__ spm, float* __restrict__ Dm) {
    __shared__ float As[8][128];
    __shared__ float Bs[8][128];
    const int tx = threadIdx.x & 15, ty = threadIdx.x >> 4;
    const int i0 = blockIdx.y * 128, j0 = blockIdx.x * 128;
    const int lr = threadIdx.x >> 1, lc = (threadIdx.x & 1) * 4;
    float acc[8][8] = {};
    for (int kk = 0; kk < 256; kk += 8) {
        float4 a4 = *(const float4*)(A + (size_t)(i0 + lr) * 256 + kk + lc);
        float4 b4 = *(const float4*)(B + (size_t)(j0 + lr) * 256 + kk + lc);
        __syncthreads();
        As[lc+0][lr] = a4.x; As[lc+1][lr] = a4.y; As[lc+2][lr] = a4.z; As[lc+3][lr] = a4.w;
        Bs[lc+0][lr] = b4.x; Bs[lc+1][lr] = b4.y; Bs[lc+2][lr] = b4.z; Bs[lc+3][lr] = b4.w;
        __syncthreads();
        #pragma unroll
        for (int k = 0; k < 8; ++k) {
            float a[8], b[8];
            *(float4*)(a)   = *(const float4*)(&As[k][ty*8]);
            *(float4*)(a+4) = *(const float4*)(&As[k][ty*8+4]);
            *(float4*)(b)   = *(const float4*)(&Bs[k][tx*8]);
            *(float4*)(b+4) = *(const float4*)(&Bs[k][tx*8+4]);
            #pragma unroll
            for (int u = 0; u < 8; ++u)
                #pragma unroll
                for (int v = 0; v < 8; ++v)
                    acc[u][v] = fmaf(a[u], b[v], acc[u][v]);
        }
    }
    float vmi[8], vmj[8];
    #pragma unroll
    for (int u = 0; u < 8; ++u) vmi[u] = 1.f - spm[i0 + ty*8 + u];
    #pragma unroll
    for (int v = 0; v < 8; ++v) vmj[v] = 1.f - spm[2048 + j0 + tx*8 + v];
    #pragma unroll
    for (int u = 0; u < 8; ++u) {
        float outv[8];
        #pragma unroll
        for (int v = 0; v < 8; ++v) {
            float s  = acc[u][v];
            float fs = fmaxf(2.f - 2.f*s, 0.f);
            outv[v] = sqrtf(fs) * expf(0.5f * vmi[u] * vmj[v]);
        }
        float* dst = Dm + (size_t)(i0 + ty*8 + u) * 2048 + j0 + tx*8;
        *(float4*)(dst)   = *(float4*)(outv);
        *(float4*)(dst+4) = *(float4*)(outv+4);
    }
}

__device__ __forceinline__ void circle_terms(float d, bool g, float& lp, float& ln) {
    if (g) { float a = d - 0.1f; lp = a > 0.f ? 24.f*a*a : 0.f; ln = 0.f; }
    else   { float b = 1.4f - d; ln = b > 0.f ? 24.f*b*b : 0.f; lp = 0.f; }
}

__device__ __forceinline__ float softplus_(float x) {
    return fmaxf(x, 0.f) + log1pf(expf(-fabsf(x)));
}

// ---------------- row logsumexp pass ----------------
__global__ __launch_bounds__(256) void k_row(const float* __restrict__ Dm,
                                             const u8* __restrict__ gt,
                                             float* __restrict__ acc) {
    const int r = blockIdx.x, t = threadIdx.x;
    const float* dp = Dm + (size_t)r * 2048 + t * 8;
    float dv[8];
    *(float4*)(dv)   = *(const float4*)(dp);
    *(float4*)(dv+4) = *(const float4*)(dp + 4);
    u64 g8 = *(const u64*)(gt + (size_t)r * 2048 + t * 8);
    float lp[8], ln[8];
    #pragma unroll
    for (int e = 0; e < 8; ++e) {
        bool g = ((g8 >> (8*e)) & 0xFFull) != 0;
        circle_terms(dv[e], g, lp[e], ln[e]);
    }
    float mp = lp[0], mn = ln[0];
    #pragma unroll
    for (int e = 1; e < 8; ++e) { mp = fmaxf(mp, lp[e]); mn = fmaxf(mn, ln[e]); }
    for (int o = 32; o; o >>= 1) { mp = fmaxf(mp, __shfl_xor(mp, o)); mn = fmaxf(mn, __shfl_xor(mn, o)); }
    __shared__ float sm[2][4];
    int w = t >> 6;
    if ((t & 63) == 0) { sm[0][w] = mp; sm[1][w] = mn; }
    __syncthreads();
    mp = fmaxf(fmaxf(sm[0][0], sm[0][1]), fmaxf(sm[0][2], sm[0][3]));
    mn = fmaxf(fmaxf(sm[1][0], sm[1][1]), fmaxf(sm[1][2], sm[1][3]));
    float sp_ = 0.f, sn_ = 0.f;
    #pragma unroll
    for (int e = 0; e < 8; ++e) { sp_ += expf(lp[e] - mp); sn_ += expf(ln[e] - mn); }
    for (int o = 32; o; o >>= 1) { sp_ += __shfl_xor(sp_, o); sn_ += __shfl_xor(sn_, o); }
    __shared__ float ss[2][4];
    if ((t & 63) == 0) { ss[0][w] = sp_; ss[1][w] = sn_; }
    __syncthreads();
    if (t == 0) {
        float SP = ss[0][0] + ss[0][1] + ss[0][2] + ss[0][3];
        float SN = ss[1][0] + ss[1][1] + ss[1][2] + ss[1][3];
        float x = (mp + logf(SP)) + (mn + logf(SN));
        atomicAdd(&acc[0], softplus_(x) * (1.f / 24.f));
    }
}

// ---------------- col logsumexp: phase 1 (partials) ----------------
__global__ __launch_bounds__(256) void k_col1(const float* __restrict__ Dm,
                                              const u8* __restrict__ gt,
                                              float* __restrict__ part) {
    const int t = threadIdx.x;
    const int cl = t & 63, rq = t >> 6;
    const int c = blockIdx.x * 64 + cl;
    const int r0 = blockIdx.y * 256;
    float mp = -INFINITY, sp_ = 0.f, mn = -INFINITY, sn_ = 0.f;
    for (int r = r0 + rq; r < r0 + 256; r += 4) {
        float d = Dm[(size_t)r * 2048 + c];
        bool g = gt[(size_t)r * 2048 + c] != 0;
        float lp, ln;
        circle_terms(d, g, lp, ln);
        float nm = fmaxf(mp, lp); sp_ = sp_ * expf(mp - nm) + expf(lp - nm); mp = nm;
        nm = fmaxf(mn, ln); sn_ = sn_ * expf(mn - nm) + expf(ln - nm); mn = nm;
    }
    __shared__ float red[4][64][4];
    red[rq][cl][0] = mp; red[rq][cl][1] = sp_; red[rq][cl][2] = mn; red[rq][cl][3] = sn_;
    __syncthreads();
    if (rq == 0) {
        float M = mp, S = sp_, Mn = mn, Sn = sn_;
        #pragma unroll
        for (int q = 1; q < 4; ++q) {
            float m2 = red[q][cl][0], s2 = red[q][cl][1];
            float nm = fmaxf(M, m2);
            S = S * expf(M - nm) + s2 * expf(m2 - nm); M = nm;
            m2 = red[q][cl][2]; s2 = red[q][cl][3];
            nm = fmaxf(Mn, m2);
            Sn = Sn * expf(Mn - nm) + s2 * expf(m2 - nm); Mn = nm;
        }
        float* p = part + ((size_t)blockIdx.y * 2048 + c) * 4;
        p[0] = M; p[1] = S; p[2] = Mn; p[3] = Sn;
    }
}

// ---------------- col logsumexp: phase 2 (merge + loss) ----------------
__global__ void k_col2(const float* __restrict__ part, float* __restrict__ acc) {
    int c = blockIdx.x * 256 + threadIdx.x;   // 0..2047
    float M = -INFINITY, S = 0.f, Mn = -INFINITY, Sn = 0.f;
    for (int q = 0; q < 8; ++q) {
        const float* p = part + ((size_t)q * 2048 + c) * 4;
        float m2 = p[0], s2 = p[1];
        float nm = fmaxf(M, m2);
        S = S * expf(M - nm) + s2 * expf(m2 - nm); M = nm;
        m2 = p[2]; s2 = p[3];
        nm = fmaxf(Mn, m2);
        Sn = Sn * expf(Mn - nm) + s2 * expf(m2 - nm); Mn = nm;
    }
    float x = (M + logf(S)) + (Mn + logf(Sn));
    float l = softplus_(x) * (1.f / 24.f);
    for (int o = 32; o; o >>= 1) l += __shfl_xor(l, o);
    __shared__ float wsum[4];
    if ((threadIdx.x & 63) == 0) wsum[threadIdx.x >> 6] = l;
    __syncthreads();
    if (threadIdx.x == 0) atomicAdd(&acc[1], wsum[0] + wsum[1] + wsum[2] + wsum[3]);
}

// ---------------- finalize ----------------
__global__ void k_fin(const float* __restrict__ acc, float* __restrict__ out) {
    float l1 = (acc[0] + acc[1]) * (0.5f / 2048.f);
    float l2 = acc[2] * (1.f / 4096.f);
    out[0] = l1 + l2; out[1] = l1; out[2] = l2;
}

extern "C" void kernel_launch(void* const* d_in, const int* in_sizes, int n_in,
                              void* d_out, int out_size, void* d_ws, size_t ws_size,
                              hipStream_t stream) {
    (void)in_sizes; (void)n_in; (void)out_size; (void)ws_size;
    const float* ref_points = (const float*)d_in[0];
    const float* src_points = (const float*)d_in[1];
    const float* ref_c      = (const float*)d_in[2];
    const float* src_c      = (const float*)d_in[3];
    const float* ref_f      = (const float*)d_in[4];
    const float* src_f      = (const float*)d_in[5];
    const int*   gti        = (const int*)d_in[6];
    const float* gtv        = (const float*)d_in[7];
    const float* spm        = (const float*)d_in[8];
    const int*   rbi        = (const int*)d_in[9];
    const int*   sbi        = (const int*)d_in[10];

    char* ws = (char*)d_ws;
    float* Dm   = (float*)(ws + OFF_D);
    u8*    gt   = (u8*)   (ws + OFF_GT);
    u64*   nn   = (u64*)  (ws + OFF_NN);
    u32*   bm   = (u32*)  (ws + OFF_BM);
    u8*    mask = (u8*)   (ws + OFF_MASK);
    u64*   cand = (u64*)  (ws + OFF_CAND);
    float* acc  = (float*)(ws + OFF_ACC);
    u32*   cnt  = (u32*)  (ws + OFF_CNT);
    float* part = (float*)(ws + OFF_PART);
    u64*   hash = (u64*)  (ws + OFF_HASH);

    hipMemsetAsync(gt, 0, (size_t)MC * NC, stream);
    k_init<<<32, 256, 0, stream>>>(nn, bm, acc, hash, cnt);
    k_bm  <<<(2*NBACK + 255)/256, 256, 0, stream>>>(rbi, sbi, bm);
    k_nn  <<<dim3(256, 2), 256, 0, stream>>>(ref_points, src_points, ref_c, src_c, nn);
    k_mask<<<16, 256, 0, stream>>>(nn, bm, spm, mask, acc);
    k_scat1<<<16, 256, 0, stream>>>(gti, mask, gt, hash);
    k_scat2<<<32, 256, 0, stream>>>(hash, gtv, mask, cand, cnt);
    k_top <<<1, 1024, 0, stream>>>(cand, cnt, gt);
    k_gemm<<<dim3(16, 16), 256, 0, stream>>>(ref_f, src_f, spm, Dm);
    k_row <<<2048, 256, 0, stream>>>(Dm, gt, acc);
    k_col1<<<dim3(32, 8), 256, 0, stream>>>(Dm, gt, part);
    k_col2<<<8, 256, 0, stream>>>(part, acc);
    k_fin <<<1, 1, 0, stream>>>(acc, (float*)d_out);
}

// Round 4
// 178.711 us; speedup vs baseline: 1.7937x; 1.1186x over previous
//
#include <hip/hip_runtime.h>
#include <math.h>

using u8  = unsigned char;
using u32 = unsigned int;
using u64 = unsigned long long;

typedef short short8 __attribute__((ext_vector_type(8)));
typedef float f32x4  __attribute__((ext_vector_type(4)));

#define MC 2048
#define NC 2048
#define DF 256
#define NFULL 50000
#define NBACK 30000
#define KCORR 4096
#define MAXPTS 256
#define NN_CHUNK 391   // 128 chunks * 391 = 50048 >= 50000

// ---------------- workspace layout ----------------
constexpr size_t OFF_D    = 0;                               // 2048*2048 f32 = 16 MB
constexpr size_t OFF_GT   = (size_t)16 * 1024 * 1024;        // 2048*2048 u8 = 4 MB
constexpr size_t OFF_NN   = OFF_GT + (size_t)4 * 1024 * 1024;        // 4096 u64
constexpr size_t BM_WORDS = 1568;                                    // ceil(50000/32)+pad
constexpr size_t OFF_BM   = OFF_NN + 4096 * 8;                       // 2*1568 u32
constexpr size_t OFF_MASK = OFF_BM + 2 * BM_WORDS * 4;               // 4096 u8
constexpr size_t OFF_CAND = OFF_MASK + 4096;                         // 4096 u64
constexpr size_t OFF_ACC  = OFF_CAND + 4096 * 8;                     // 8 f32
constexpr size_t OFF_CNT  = OFF_ACC + 256;                           // 1 u32 (+pad)
constexpr size_t OFF_PART = OFF_CNT + 256;                           // 8*2048*4 f32 = 256 KB
constexpr size_t OFF_HASH = OFF_PART + (size_t)8 * 2048 * 4 * 4;     // 8192 u64 = 64 KB

// ---------------- init ----------------
__global__ void k_init(u64* __restrict__ nn, u32* __restrict__ bm, float* __restrict__ acc,
                       u64* __restrict__ hash, u32* __restrict__ cnt) {
    int e = blockIdx.x * 256 + threadIdx.x;   // 0..8191
    if (e < 4096) nn[e] = ~0ull;
    if (e < (int)(2 * BM_WORDS)) bm[e] = 0u;
    if (e < 8) acc[e] = 0.f;
    if (e == 0) *cnt = 0u;
    hash[e] = 0ull;
}

// ---------------- back-index bitmaps ----------------
__global__ void k_bm(const int* __restrict__ rb, const int* __restrict__ sb, u32* __restrict__ bm) {
    int e = blockIdx.x * 256 + threadIdx.x;
    if (e < NBACK) {
        int v = rb[e];
        atomicOr(&bm[v >> 5], 1u << (v & 31));
    } else if (e < 2*NBACK) {
        int v = sb[e - NBACK];
        atomicOr(&bm[BM_WORDS + (v >> 5)], 1u << (v & 31));
    }
}

// ---------------- NN argmin ----------------
__global__ __launch_bounds__(256) void k_nn(
        const float* __restrict__ fr, const float* __restrict__ fs,
        const float* __restrict__ cr, const float* __restrict__ cs,
        u64* __restrict__ nn) {
    const int side = blockIdx.y;
    const float* full = side ? fs : fr;
    const float* corr = side ? cs : cr;
    const int ib = blockIdx.x & 1, ch = blockIdx.x >> 1;
    const int t = threadIdx.x;

    __shared__ float4 s4[NN_CHUNK];
    const int j0 = ch * NN_CHUNK;
    for (int e = t; e < NN_CHUNK; e += 256) {
        int j = j0 + e;
        float4 v;
        if (j < NFULL) {
            float x = full[j*3], y = full[j*3+1], z = full[j*3+2];
            v = make_float4(x, y, z, x*x + y*y + z*z);
        } else {
            v = make_float4(0.f, 0.f, 0.f, 3.0e38f);   // sentinel: never wins
        }
        s4[e] = v;
    }

    float ax[4], ay[4], az[4], bd[4];
    u32 bj[4];
    #pragma unroll
    for (int q = 0; q < 4; ++q) {
        int i = ib * 1024 + q * 256 + t;
        float cx = corr[i*3], cy = corr[i*3+1], cz = corr[i*3+2];
        ax[q] = -2.f*cx; ay[q] = -2.f*cy; az[q] = -2.f*cz;
        bd[q] = 3.4e38f; bj[q] = 0u;
    }
    __syncthreads();

    #pragma unroll 4
    for (int jj = 0; jj < NN_CHUNK; ++jj) {
        float4 p = s4[jj];
        #pragma unroll
        for (int q = 0; q < 4; ++q) {
            float d = fmaf(ax[q], p.x, fmaf(ay[q], p.y, fmaf(az[q], p.z, p.w)));
            if (d < bd[q]) { bd[q] = d; bj[q] = (u32)(j0 + jj); }
        }
    }

    #pragma unroll
    for (int q = 0; q < 4; ++q) {
        int i = ib * 1024 + q * 256 + t;
        float cn = 0.25f * fmaf(ax[q], ax[q], fmaf(ay[q], ay[q], az[q]*az[q]));
        float bf = bd[q] + cn;
        u32 db = __float_as_uint(bf);
        db = (db & 0x80000000u) ? ~db : (db | 0x80000000u);
        atomicMin(&nn[side * 2048 + i], ((u64)db << 32) | bj[q]);
    }
}

// ---------------- masks + loss2 ----------------
__global__ void k_mask(const u64* __restrict__ nn, const u32* __restrict__ bm,
                       const float* __restrict__ spm, u8* __restrict__ mask,
                       float* __restrict__ acc) {
    int t = blockIdx.x * 256 + threadIdx.x;   // 0..4095
    int side = t >> 11;
    u32 j = (u32)(nn[t] & 0xFFFFFFFFull);
    u32 bit = (bm[side * BM_WORDS + (j >> 5)] >> (j & 31)) & 1u;
    mask[t] = (u8)bit;
    float c = fabsf((1.f - spm[t]) - (float)bit);
    for (int o = 32; o; o >>= 1) c += __shfl_xor(c, o);
    __shared__ float wsum[4];
    if ((threadIdx.x & 63) == 0) wsum[threadIdx.x >> 6] = c;
    __syncthreads();
    if (threadIdx.x == 0) atomicAdd(&acc[2], wsum[0] + wsum[1] + wsum[2] + wsum[3]);
}

// ---------------- scatter phase 1: gt set + last-wins dedup via hash ----------------
__global__ void k_scat1(const int* __restrict__ gti, const u8* __restrict__ mask,
                        u8* __restrict__ gt, u64* __restrict__ hash) {
    int k = blockIdx.x * 256 + threadIdx.x;   // 0..4095
    int xi = gti[2*k], yi = gti[2*k+1];
    u32 cell = (u32)(xi * 2048 + yi);
    if (mask[xi] && mask[2048 + yi]) gt[cell] = 1;
    u64 val = ((u64)(cell + 1) << 12) | (u32)k;
    u32 h = (cell * 2654435761u) >> 19;       // 13-bit hash -> 8192 slots
    while (true) {
        u64 cur = hash[h];
        if ((cur >> 12) == (u64)(cell + 1)) { atomicMax(&hash[h], val); return; }
        if (cur == 0ull) {
            u64 prev = atomicCAS(&hash[h], 0ull, val);
            if (prev == 0ull) return;
            if ((prev >> 12) == (u64)(cell + 1)) { atomicMax(&hash[h], val); return; }
        }
        h = (h + 1) & 8191;
    }
}

// ---------------- scatter phase 2: collect masked candidates ----------------
__global__ void k_scat2(const u64* __restrict__ hash, const float* __restrict__ gtv,
                        const u8* __restrict__ mask, u64* __restrict__ cand,
                        u32* __restrict__ cnt) {
    int e = blockIdx.x * 256 + threadIdx.x;   // 0..8191
    u64 s = hash[e];
    if (s == 0ull) return;
    u32 cell = (u32)(s >> 12) - 1u;
    int xi = cell >> 11, yi = cell & 2047;
    if (!(mask[xi] && mask[2048 + yi])) return;
    u32 k = (u32)(s & 0xFFFull);
    u32 vb = __float_as_uint(gtv[k]);         // overlaps >= 0 -> bits monotonic
    u32 idx = atomicAdd(cnt, 1u);
    cand[idx] = ((u64)vb << 22) | (u32)(0x3FFFFF - cell);
}

// ---------------- scatter phase 3: top-256 cap via O(n^2) rank ----------------
__global__ __launch_bounds__(1024) void k_top(const u64* __restrict__ cand,
                                              const u32* __restrict__ cnt,
                                              u8* __restrict__ gt) {
    __shared__ u64 keys[4096];
    const int n = (int)*cnt;
    if (n <= MAXPTS) return;
    const int t = threadIdx.x;
    for (int e = t; e < n; e += 1024) keys[e] = cand[e];
    __syncthreads();
    for (int c = t; c < n; c += 1024) {
        u64 me = keys[c];
        int rank = 0;
        for (int j = 0; j < n; ++j) rank += (keys[j] > me);
        if (rank >= MAXPTS) {
            u32 cell = 0x3FFFFFu - (u32)(me & 0x3FFFFFull);
            gt[cell] = 0;
        }
    }
}

// ---------------- MFMA bf16 GEMM + laplace epilogue -> d matrix ----------------
// 128x128 tile, BK=128, 4 waves (2x2), each wave 64x64 = 4x4 frags of 16x16x32.
// LDS fragment-major: frag = 1024B of [q(0..3)][r(0..15)] 16B chunks, so every
// ds_read_b128 is frag_base + lane*16 (linear, conflict-free).
// f32 -> bf16 RNE conversion fused into register staging (f32 inputs are L2-resident).
__device__ __forceinline__ short f2bf(float f) {
    u32 x = __float_as_uint(f);
    return (short)((x + 0x7fffu + ((x >> 16) & 1u)) >> 16);
}

__global__ __launch_bounds__(256) void k_gemm(
        const float* __restrict__ A, const float* __restrict__ B,
        const float* __restrict__ spm, float* __restrict__ Dm) {
    __shared__ __align__(16) short As[16384];   // 32 KB: 32 frags (8m x 4k)
    __shared__ __align__(16) short Bs[16384];
    const int t = threadIdx.x;
    const int l = t & 63, wid = t >> 6;
    const int wm = wid >> 1, wn = wid & 1;
    const int i0 = blockIdx.y * 128, j0 = blockIdx.x * 128;

    f32x4 acc[4][4] = {};

    for (int ks = 0; ks < 2; ++ks) {
        __syncthreads();
        #pragma unroll
        for (int it = 0; it < 8; ++it) {
            int sl = it * 256 + t;                 // 0..2047 slots of 16B
            int g = sl >> 6, c = sl & 63;
            int q = c >> 4, r15 = c & 15;
            int row = (g >> 2) * 16 + r15;
            int col = ks * 128 + (g & 3) * 32 + q * 8;
            const float* ap = A + (size_t)(i0 + row) * 256 + col;
            const float* bp = B + (size_t)(j0 + row) * 256 + col;
            float4 a0 = *(const float4*)(ap), a1 = *(const float4*)(ap + 4);
            float4 b0 = *(const float4*)(bp), b1 = *(const float4*)(bp + 4);
            short8 va, vb;
            va[0]=f2bf(a0.x); va[1]=f2bf(a0.y); va[2]=f2bf(a0.z); va[3]=f2bf(a0.w);
            va[4]=f2bf(a1.x); va[5]=f2bf(a1.y); va[6]=f2bf(a1.z); va[7]=f2bf(a1.w);
            vb[0]=f2bf(b0.x); vb[1]=f2bf(b0.y); vb[2]=f2bf(b0.z); vb[3]=f2bf(b0.w);
            vb[4]=f2bf(b1.x); vb[5]=f2bf(b1.y); vb[6]=f2bf(b1.z); vb[7]=f2bf(b1.w);
            *(short8*)&As[sl * 8] = va;
            *(short8*)&Bs[sl * 8] = vb;
        }
        __syncthreads();

        #pragma unroll
        for (int kf = 0; kf < 4; ++kf) {
            short8 a[4], b[4];
            #pragma unroll
            for (int mi = 0; mi < 4; ++mi)
                a[mi] = *(const short8*)&As[(((wm*4 + mi)*4 + kf) << 9) + l*8];
            #pragma unroll
            for (int ni = 0; ni < 4; ++ni)
                b[ni] = *(const short8*)&Bs[(((wn*4 + ni)*4 + kf) << 9) + l*8];
            #pragma unroll
            for (int mi = 0; mi < 4; ++mi)
                #pragma unroll
                for (int ni = 0; ni < 4; ++ni)
                    acc[mi][ni] = __builtin_amdgcn_mfma_f32_16x16x32_bf16(
                        a[mi], b[ni], acc[mi][ni], 0, 0, 0);
        }
    }

    // epilogue: C/D layout col=lane&15, row=(lane>>4)*4+reg  [m89-verified]
    const int cq = l >> 4, cr = l & 15;
    float vmi[4][4];
    #pragma unroll
    for (int mi = 0; mi < 4; ++mi)
        #pragma unroll
        for (int r = 0; r < 4; ++r)
            vmi[mi][r] = 1.f - spm[i0 + wm*64 + mi*16 + cq*4 + r];
    #pragma unroll
    for (int ni = 0; ni < 4; ++ni) {
        int col = j0 + wn*64 + ni*16 + cr;
        float vmj = 1.f - spm[2048 + col];
        #pragma unroll
        for (int mi = 0; mi < 4; ++mi) {
            #pragma unroll
            for (int r = 0; r < 4; ++r) {
                int row = i0 + wm*64 + mi*16 + cq*4 + r;
                float s  = acc[mi][ni][r];
                float fs = fmaxf(2.f - 2.f*s, 0.f);
                Dm[(size_t)row * 2048 + col] = sqrtf(fs) * expf(0.5f * vmi[mi][r] * vmj);
            }
        }
    }
}

__device__ __forceinline__ void circle_terms(float d, bool g, float& lp, float& ln) {
    if (g) { float a = d - 0.1f; lp = a > 0.f ? 24.f*a*a : 0.f; ln = 0.f; }
    else   { float b = 1.4f - d; ln = b > 0.f ? 24.f*b*b : 0.f; lp = 0.f; }
}

__device__ __forceinline__ float softplus_(float x) {
    return fmaxf(x, 0.f) + log1pf(expf(-fabsf(x)));
}

// ---------------- row logsumexp pass ----------------
__global__ __launch_bounds__(256) void k_row(const float* __restrict__ Dm,
                                             const u8* __restrict__ gt,
                                             float* __restrict__ acc) {
    const int r = blockIdx.x, t = threadIdx.x;
    const float* dp = Dm + (size_t)r * 2048 + t * 8;
    float dv[8];
    *(float4*)(dv)   = *(const float4*)(dp);
    *(float4*)(dv+4) = *(const float4*)(dp + 4);
    u64 g8 = *(const u64*)(gt + (size_t)r * 2048 + t * 8);
    float lp[8], ln[8];
    #pragma unroll
    for (int e = 0; e < 8; ++e) {
        bool g = ((g8 >> (8*e)) & 0xFFull) != 0;
        circle_terms(dv[e], g, lp[e], ln[e]);
    }
    float mp = lp[0], mn = ln[0];
    #pragma unroll
    for (int e = 1; e < 8; ++e) { mp = fmaxf(mp, lp[e]); mn = fmaxf(mn, ln[e]); }
    for (int o = 32; o; o >>= 1) { mp = fmaxf(mp, __shfl_xor(mp, o)); mn = fmaxf(mn, __shfl_xor(mn, o)); }
    __shared__ float sm[2][4];
    int w = t >> 6;
    if ((t & 63) == 0) { sm[0][w] = mp; sm[1][w] = mn; }
    __syncthreads();
    mp = fmaxf(fmaxf(sm[0][0], sm[0][1]), fmaxf(sm[0][2], sm[0][3]));
    mn = fmaxf(fmaxf(sm[1][0], sm[1][1]), fmaxf(sm[1][2], sm[1][3]));
    float sp_ = 0.f, sn_ = 0.f;
    #pragma unroll
    for (int e = 0; e < 8; ++e) { sp_ += expf(lp[e] - mp); sn_ += expf(ln[e] - mn); }
    for (int o = 32; o; o >>= 1) { sp_ += __shfl_xor(sp_, o); sn_ += __shfl_xor(sn_, o); }
    __shared__ float ss[2][4];
    if ((t & 63) == 0) { ss[0][w] = sp_; ss[1][w] = sn_; }
    __syncthreads();
    if (t == 0) {
        float SP = ss[0][0] + ss[0][1] + ss[0][2] + ss[0][3];
        float SN = ss[1][0] + ss[1][1] + ss[1][2] + ss[1][3];
        float x = (mp + logf(SP)) + (mn + logf(SN));
        atomicAdd(&acc[0], softplus_(x) * (1.f / 24.f));
    }
}

// ---------------- col logsumexp: phase 1 (partials) ----------------
__global__ __launch_bounds__(256) void k_col1(const float* __restrict__ Dm,
                                              const u8* __restrict__ gt,
                                              float* __restrict__ part) {
    const int t = threadIdx.x;
    const int cl = t & 63, rq = t >> 6;
    const int c = blockIdx.x * 64 + cl;
    const int r0 = blockIdx.y * 256;
    float mp = -INFINITY, sp_ = 0.f, mn = -INFINITY, sn_ = 0.f;
    for (int r = r0 + rq; r < r0 + 256; r += 4) {
        float d = Dm[(size_t)r * 2048 + c];
        bool g = gt[(size_t)r * 2048 + c] != 0;
        float lp, ln;
        circle_terms(d, g, lp, ln);
        float nm = fmaxf(mp, lp); sp_ = sp_ * expf(mp - nm) + expf(lp - nm); mp = nm;
        nm = fmaxf(mn, ln); sn_ = sn_ * expf(mn - nm) + expf(ln - nm); mn = nm;
    }
    __shared__ float red[4][64][4];
    red[rq][cl][0] = mp; red[rq][cl][1] = sp_; red[rq][cl][2] = mn; red[rq][cl][3] = sn_;
    __syncthreads();
    if (rq == 0) {
        float M = mp, S = sp_, Mn = mn, Sn = sn_;
        #pragma unroll
        for (int q = 1; q < 4; ++q) {
            float m2 = red[q][cl][0], s2 = red[q][cl][1];
            float nm = fmaxf(M, m2);
            S = S * expf(M - nm) + s2 * expf(m2 - nm); M = nm;
            m2 = red[q][cl][2]; s2 = red[q][cl][3];
            nm = fmaxf(Mn, m2);
            Sn = Sn * expf(Mn - nm) + s2 * expf(m2 - nm); Mn = nm;
        }
        float* p = part + ((size_t)blockIdx.y * 2048 + c) * 4;
        p[0] = M; p[1] = S; p[2] = Mn; p[3] = Sn;
    }
}

// ---------------- col logsumexp: phase 2 (merge + loss) ----------------
__global__ void k_col2(const float* __restrict__ part, float* __restrict__ acc) {
    int c = blockIdx.x * 256 + threadIdx.x;   // 0..2047
    float M = -INFINITY, S = 0.f, Mn = -INFINITY, Sn = 0.f;
    for (int q = 0; q < 8; ++q) {
        const float* p = part + ((size_t)q * 2048 + c) * 4;
        float m2 = p[0], s2 = p[1];
        float nm = fmaxf(M, m2);
        S = S * expf(M - nm) + s2 * expf(m2 - nm); M = nm;
        m2 = p[2]; s2 = p[3];
        nm = fmaxf(Mn, m2);
        Sn = Sn * expf(Mn - nm) + s2 * expf(m2 - nm); Mn = nm;
    }
    float x = (M + logf(S)) + (Mn + logf(Sn));
    float l = softplus_(x) * (1.f / 24.f);
    for (int o = 32; o; o >>= 1) l += __shfl_xor(l, o);
    __shared__ float wsum[4];
    if ((threadIdx.x & 63) == 0) wsum[threadIdx.x >> 6] = l;
    __syncthreads();
    if (threadIdx.x == 0) atomicAdd(&acc[1], wsum[0] + wsum[1] + wsum[2] + wsum[3]);
}

// ---------------- finalize ----------------
__global__ void k_fin(const float* __restrict__ acc, float* __restrict__ out) {
    float l1 = (acc[0] + acc[1]) * (0.5f / 2048.f);
    float l2 = acc[2] * (1.f / 4096.f);
    out[0] = l1 + l2; out[1] = l1; out[2] = l2;
}

extern "C" void kernel_launch(void* const* d_in, const int* in_sizes, int n_in,
                              void* d_out, int out_size, void* d_ws, size_t ws_size,
                              hipStream_t stream) {
    (void)in_sizes; (void)n_in; (void)out_size; (void)ws_size;
    const float* ref_points = (const float*)d_in[0];
    const float* src_points = (const float*)d_in[1];
    const float* ref_c      = (const float*)d_in[2];
    const float* src_c      = (const float*)d_in[3];
    const float* ref_f      = (const float*)d_in[4];
    const float* src_f      = (const float*)d_in[5];
    const int*   gti        = (const int*)d_in[6];
    const float* gtv        = (const float*)d_in[7];
    const float* spm        = (const float*)d_in[8];
    const int*   rbi        = (const int*)d_in[9];
    const int*   sbi        = (const int*)d_in[10];

    char* ws = (char*)d_ws;
    float* Dm   = (float*)(ws + OFF_D);
    u8*    gt   = (u8*)   (ws + OFF_GT);
    u64*   nn   = (u64*)  (ws + OFF_NN);
    u32*   bm   = (u32*)  (ws + OFF_BM);
    u8*    mask = (u8*)   (ws + OFF_MASK);
    u64*   cand = (u64*)  (ws + OFF_CAND);
    float* acc  = (float*)(ws + OFF_ACC);
    u32*   cnt  = (u32*)  (ws + OFF_CNT);
    float* part = (float*)(ws + OFF_PART);
    u64*   hash = (u64*)  (ws + OFF_HASH);

    hipMemsetAsync(gt, 0, (size_t)MC * NC, stream);
    k_init<<<32, 256, 0, stream>>>(nn, bm, acc, hash, cnt);
    k_bm  <<<(2*NBACK + 255)/256, 256, 0, stream>>>(rbi, sbi, bm);
    k_nn  <<<dim3(256, 2), 256, 0, stream>>>(ref_points, src_points, ref_c, src_c, nn);
    k_mask<<<16, 256, 0, stream>>>(nn, bm, spm, mask, acc);
    k_scat1<<<16, 256, 0, stream>>>(gti, mask, gt, hash);
    k_scat2<<<32, 256, 0, stream>>>(hash, gtv, mask, cand, cnt);
    k_top <<<1, 1024, 0, stream>>>(cand, cnt, gt);
    k_gemm<<<dim3(16, 16), 256, 0, stream>>>(ref_f, src_f, spm, Dm);
    k_row <<<2048, 256, 0, stream>>>(Dm, gt, acc);
    k_col1<<<dim3(32, 8), 256, 0, stream>>>(Dm, gt, part);
    k_col2<<<8, 256, 0, stream>>>(part, acc);
    k_fin <<<1, 1, 0, stream>>>(acc, (float*)d_out);
}

// Round 5
// 176.820 us; speedup vs baseline: 1.8129x; 1.0107x over previous
//
#include <hip/hip_runtime.h>
#include <math.h>

using u8  = unsigned char;
using u32 = unsigned int;
using u64 = unsigned long long;

typedef short short8 __attribute__((ext_vector_type(8)));
typedef float f32x4  __attribute__((ext_vector_type(4)));

#define MC 2048
#define NC 2048
#define DF 256
#define NFULL 50000
#define NBACK 30000
#define KCORR 4096
#define MAXPTS 256
#define NN_CHUNK 391   // 128 chunks * 391 = 50048 >= 50000

// ---------------- workspace layout ----------------
constexpr size_t OFF_D    = 0;                               // 2048*2048 f32 = 16 MB
constexpr size_t OFF_GT   = (size_t)16 * 1024 * 1024;        // 2048*2048 u8 = 4 MB
constexpr size_t OFF_NN   = OFF_GT + (size_t)4 * 1024 * 1024;        // 4096 u64
constexpr size_t BM_WORDS = 1568;                                    // ceil(50000/32)+pad
constexpr size_t OFF_BM   = OFF_NN + 4096 * 8;                       // 2*1568 u32
constexpr size_t OFF_MASK = OFF_BM + 2 * BM_WORDS * 4;               // 4096 u8
constexpr size_t OFF_CAND = OFF_MASK + 4096;                         // 4096 u64
constexpr size_t OFF_ACC  = OFF_CAND + 4096 * 8;                     // 8 f32
constexpr size_t OFF_CNT  = OFF_ACC + 256;                           // 1 u32 (+pad)
constexpr size_t OFF_PART = OFF_CNT + 256;                           // 8*2048*4 f32 = 256 KB
constexpr size_t OFF_HASH = OFF_PART + (size_t)8 * 2048 * 4 * 4;     // 8192 u64 = 64 KB

// ---------------- init (also zeroes gt: 1024 blocks x 256 thr x 16B = 4 MB) ----------------
__global__ __launch_bounds__(256) void k_init(u64* __restrict__ nn, u32* __restrict__ bm,
                       float* __restrict__ acc, u64* __restrict__ hash, u32* __restrict__ cnt,
                       uint4* __restrict__ gt4) {
    int e = blockIdx.x * 256 + threadIdx.x;   // 0..262143
    gt4[e] = make_uint4(0u, 0u, 0u, 0u);
    if (e < 8192) hash[e] = 0ull;
    if (e < 4096) nn[e] = ~0ull;
    if (e < (int)(2 * BM_WORDS)) bm[e] = 0u;
    if (e < 8) acc[e] = 0.f;
    if (e == 0) *cnt = 0u;
}

// ---------------- back-index bitmaps ----------------
__global__ void k_bm(const int* __restrict__ rb, const int* __restrict__ sb, u32* __restrict__ bm) {
    int e = blockIdx.x * 256 + threadIdx.x;
    if (e < NBACK) {
        int v = rb[e];
        atomicOr(&bm[v >> 5], 1u << (v & 31));
    } else if (e < 2*NBACK) {
        int v = sb[e - NBACK];
        atomicOr(&bm[BM_WORDS + (v >> 5)], 1u << (v & 31));
    }
}

// ---------------- NN argmin ----------------
__global__ __launch_bounds__(256) void k_nn(
        const float* __restrict__ fr, const float* __restrict__ fs,
        const float* __restrict__ cr, const float* __restrict__ cs,
        u64* __restrict__ nn) {
    const int side = blockIdx.y;
    const float* full = side ? fs : fr;
    const float* corr = side ? cs : cr;
    const int ib = blockIdx.x & 1, ch = blockIdx.x >> 1;
    const int t = threadIdx.x;

    __shared__ float4 s4[NN_CHUNK];
    const int j0 = ch * NN_CHUNK;
    for (int e = t; e < NN_CHUNK; e += 256) {
        int j = j0 + e;
        float4 v;
        if (j < NFULL) {
            float x = full[j*3], y = full[j*3+1], z = full[j*3+2];
            v = make_float4(x, y, z, x*x + y*y + z*z);
        } else {
            v = make_float4(0.f, 0.f, 0.f, 3.0e38f);   // sentinel: never wins
        }
        s4[e] = v;
    }

    float ax[4], ay[4], az[4], bd[4];
    u32 bj[4];
    #pragma unroll
    for (int q = 0; q < 4; ++q) {
        int i = ib * 1024 + q * 256 + t;
        float cx = corr[i*3], cy = corr[i*3+1], cz = corr[i*3+2];
        ax[q] = -2.f*cx; ay[q] = -2.f*cy; az[q] = -2.f*cz;
        bd[q] = 3.4e38f; bj[q] = 0u;
    }
    __syncthreads();

    #pragma unroll 4
    for (int jj = 0; jj < NN_CHUNK; ++jj) {
        float4 p = s4[jj];
        #pragma unroll
        for (int q = 0; q < 4; ++q) {
            float d = fmaf(ax[q], p.x, fmaf(ay[q], p.y, fmaf(az[q], p.z, p.w)));
            if (d < bd[q]) { bd[q] = d; bj[q] = (u32)(j0 + jj); }
        }
    }

    #pragma unroll
    for (int q = 0; q < 4; ++q) {
        int i = ib * 1024 + q * 256 + t;
        float cn = 0.25f * fmaf(ax[q], ax[q], fmaf(ay[q], ay[q], az[q]*az[q]));
        float bf = bd[q] + cn;
        u32 db = __float_as_uint(bf);
        db = (db & 0x80000000u) ? ~db : (db | 0x80000000u);
        atomicMin(&nn[side * 2048 + i], ((u64)db << 32) | bj[q]);
    }
}

// ---------------- masks + loss2 ----------------
__global__ void k_mask(const u64* __restrict__ nn, const u32* __restrict__ bm,
                       const float* __restrict__ spm, u8* __restrict__ mask,
                       float* __restrict__ acc) {
    int t = blockIdx.x * 256 + threadIdx.x;   // 0..4095
    int side = t >> 11;
    u32 j = (u32)(nn[t] & 0xFFFFFFFFull);
    u32 bit = (bm[side * BM_WORDS + (j >> 5)] >> (j & 31)) & 1u;
    mask[t] = (u8)bit;
    float c = fabsf((1.f - spm[t]) - (float)bit);
    for (int o = 32; o; o >>= 1) c += __shfl_xor(c, o);
    __shared__ float wsum[4];
    if ((threadIdx.x & 63) == 0) wsum[threadIdx.x >> 6] = c;
    __syncthreads();
    if (threadIdx.x == 0) atomicAdd(&acc[2], wsum[0] + wsum[1] + wsum[2] + wsum[3]);
}

// ---------------- scatter phase 1: gt set + last-wins dedup via hash ----------------
__global__ void k_scat1(const int* __restrict__ gti, const u8* __restrict__ mask,
                        u8* __restrict__ gt, u64* __restrict__ hash) {
    int k = blockIdx.x * 256 + threadIdx.x;   // 0..4095
    int xi = gti[2*k], yi = gti[2*k+1];
    u32 cell = (u32)(xi * 2048 + yi);
    if (mask[xi] && mask[2048 + yi]) gt[cell] = 1;
    u64 val = ((u64)(cell + 1) << 12) | (u32)k;
    u32 h = (cell * 2654435761u) >> 19;       // 13-bit hash -> 8192 slots
    while (true) {
        u64 cur = hash[h];
        if ((cur >> 12) == (u64)(cell + 1)) { atomicMax(&hash[h], val); return; }
        if (cur == 0ull) {
            u64 prev = atomicCAS(&hash[h], 0ull, val);
            if (prev == 0ull) return;
            if ((prev >> 12) == (u64)(cell + 1)) { atomicMax(&hash[h], val); return; }
        }
        h = (h + 1) & 8191;
    }
}

// ---------------- scatter phase 2: collect masked candidates ----------------
__global__ void k_scat2(const u64* __restrict__ hash, const float* __restrict__ gtv,
                        const u8* __restrict__ mask, u64* __restrict__ cand,
                        u32* __restrict__ cnt) {
    int e = blockIdx.x * 256 + threadIdx.x;   // 0..8191
    u64 s = hash[e];
    if (s == 0ull) return;
    u32 cell = (u32)(s >> 12) - 1u;
    int xi = cell >> 11, yi = cell & 2047;
    if (!(mask[xi] && mask[2048 + yi])) return;
    u32 k = (u32)(s & 0xFFFull);
    u32 vb = __float_as_uint(gtv[k]);         // overlaps >= 0 -> bits monotonic
    u32 idx = atomicAdd(cnt, 1u);
    cand[idx] = ((u64)vb << 22) | (u32)(0x3FFFFF - cell);
}

// ---------------- scatter phase 3: top-256 cap via O(n^2) rank ----------------
__global__ __launch_bounds__(1024) void k_top(const u64* __restrict__ cand,
                                              const u32* __restrict__ cnt,
                                              u8* __restrict__ gt) {
    __shared__ u64 keys[4096];
    const int n = (int)*cnt;
    if (n <= MAXPTS) return;
    const int t = threadIdx.x;
    for (int e = t; e < n; e += 1024) keys[e] = cand[e];
    __syncthreads();
    for (int c = t; c < n; c += 1024) {
        u64 me = keys[c];
        int rank = 0;
        for (int j = 0; j < n; ++j) rank += (keys[j] > me);
        if (rank >= MAXPTS) {
            u32 cell = 0x3FFFFFu - (u32)(me & 0x3FFFFFull);
            gt[cell] = 0;
        }
    }
}

// ---------------- MFMA bf16 GEMM + laplace epilogue -> d matrix ----------------
__device__ __forceinline__ short f2bf(float f) {
    u32 x = __float_as_uint(f);
    return (short)((x + 0x7fffu + ((x >> 16) & 1u)) >> 16);
}

__global__ __launch_bounds__(256) void k_gemm(
        const float* __restrict__ A, const float* __restrict__ B,
        const float* __restrict__ spm, float* __restrict__ Dm) {
    __shared__ __align__(16) short As[16384];   // 32 KB: 32 frags (8m x 4k)
    __shared__ __align__(16) short Bs[16384];
    const int t = threadIdx.x;
    const int l = t & 63, wid = t >> 6;
    const int wm = wid >> 1, wn = wid & 1;
    const int i0 = blockIdx.y * 128, j0 = blockIdx.x * 128;

    f32x4 acc[4][4] = {};

    for (int ks = 0; ks < 2; ++ks) {
        __syncthreads();
        #pragma unroll
        for (int it = 0; it < 8; ++it) {
            int sl = it * 256 + t;                 // 0..2047 slots of 16B
            int g = sl >> 6, c = sl & 63;
            int q = c >> 4, r15 = c & 15;
            int row = (g >> 2) * 16 + r15;
            int col = ks * 128 + (g & 3) * 32 + q * 8;
            const float* ap = A + (size_t)(i0 + row) * 256 + col;
            const float* bp = B + (size_t)(j0 + row) * 256 + col;
            float4 a0 = *(const float4*)(ap), a1 = *(const float4*)(ap + 4);
            float4 b0 = *(const float4*)(bp), b1 = *(const float4*)(bp + 4);
            short8 va, vb;
            va[0]=f2bf(a0.x); va[1]=f2bf(a0.y); va[2]=f2bf(a0.z); va[3]=f2bf(a0.w);
            va[4]=f2bf(a1.x); va[5]=f2bf(a1.y); va[6]=f2bf(a1.z); va[7]=f2bf(a1.w);
            vb[0]=f2bf(b0.x); vb[1]=f2bf(b0.y); vb[2]=f2bf(b0.z); vb[3]=f2bf(b0.w);
            vb[4]=f2bf(b1.x); vb[5]=f2bf(b1.y); vb[6]=f2bf(b1.z); vb[7]=f2bf(b1.w);
            *(short8*)&As[sl * 8] = va;
            *(short8*)&Bs[sl * 8] = vb;
        }
        __syncthreads();

        #pragma unroll
        for (int kf = 0; kf < 4; ++kf) {
            short8 a[4], b[4];
            #pragma unroll
            for (int mi = 0; mi < 4; ++mi)
                a[mi] = *(const short8*)&As[(((wm*4 + mi)*4 + kf) << 9) + l*8];
            #pragma unroll
            for (int ni = 0; ni < 4; ++ni)
                b[ni] = *(const short8*)&Bs[(((wn*4 + ni)*4 + kf) << 9) + l*8];
            #pragma unroll
            for (int mi = 0; mi < 4; ++mi)
                #pragma unroll
                for (int ni = 0; ni < 4; ++ni)
                    acc[mi][ni] = __builtin_amdgcn_mfma_f32_16x16x32_bf16(
                        a[mi], b[ni], acc[mi][ni], 0, 0, 0);
        }
    }

    // epilogue: C/D layout col=lane&15, row=(lane>>4)*4+reg  [m89-verified]
    const int cq = l >> 4, cr = l & 15;
    float vmi[4][4];
    #pragma unroll
    for (int mi = 0; mi < 4; ++mi)
        #pragma unroll
        for (int r = 0; r < 4; ++r)
            vmi[mi][r] = 1.f - spm[i0 + wm*64 + mi*16 + cq*4 + r];
    #pragma unroll
    for (int ni = 0; ni < 4; ++ni) {
        int col = j0 + wn*64 + ni*16 + cr;
        float vmj = 1.f - spm[2048 + col];
        #pragma unroll
        for (int mi = 0; mi < 4; ++mi) {
            #pragma unroll
            for (int r = 0; r < 4; ++r) {
                int row = i0 + wm*64 + mi*16 + cq*4 + r;
                float s  = acc[mi][ni][r];
                float fs = fmaxf(2.f - 2.f*s, 0.f);
                Dm[(size_t)row * 2048 + col] = sqrtf(fs) * expf(0.5f * vmi[mi][r] * vmj);
            }
        }
    }
}

__device__ __forceinline__ void circle_terms(float d, bool g, float& lp, float& ln) {
    if (g) { float a = d - 0.1f; lp = a > 0.f ? 24.f*a*a : 0.f; ln = 0.f; }
    else   { float b = 1.4f - d; ln = b > 0.f ? 24.f*b*b : 0.f; lp = 0.f; }
}

__device__ __forceinline__ float softplus_(float x) {
    return fmaxf(x, 0.f) + log1pf(expf(-fabsf(x)));
}

// ---------------- row logsumexp pass ----------------
__global__ __launch_bounds__(256) void k_row(const float* __restrict__ Dm,
                                             const u8* __restrict__ gt,
                                             float* __restrict__ acc) {
    const int r = blockIdx.x, t = threadIdx.x;
    const float* dp = Dm + (size_t)r * 2048 + t * 8;
    float dv[8];
    *(float4*)(dv)   = *(const float4*)(dp);
    *(float4*)(dv+4) = *(const float4*)(dp + 4);
    u64 g8 = *(const u64*)(gt + (size_t)r * 2048 + t * 8);
    float lp[8], ln[8];
    #pragma unroll
    for (int e = 0; e < 8; ++e) {
        bool g = ((g8 >> (8*e)) & 0xFFull) != 0;
        circle_terms(dv[e], g, lp[e], ln[e]);
    }
    float mp = lp[0], mn = ln[0];
    #pragma unroll
    for (int e = 1; e < 8; ++e) { mp = fmaxf(mp, lp[e]); mn = fmaxf(mn, ln[e]); }
    for (int o = 32; o; o >>= 1) { mp = fmaxf(mp, __shfl_xor(mp, o)); mn = fmaxf(mn, __shfl_xor(mn, o)); }
    __shared__ float sm[2][4];
    int w = t >> 6;
    if ((t & 63) == 0) { sm[0][w] = mp; sm[1][w] = mn; }
    __syncthreads();
    mp = fmaxf(fmaxf(sm[0][0], sm[0][1]), fmaxf(sm[0][2], sm[0][3]));
    mn = fmaxf(fmaxf(sm[1][0], sm[1][1]), fmaxf(sm[1][2], sm[1][3]));
    float sp_ = 0.f, sn_ = 0.f;
    #pragma unroll
    for (int e = 0; e < 8; ++e) { sp_ += expf(lp[e] - mp); sn_ += expf(ln[e] - mn); }
    for (int o = 32; o; o >>= 1) { sp_ += __shfl_xor(sp_, o); sn_ += __shfl_xor(sn_, o); }
    __shared__ float ss[2][4];
    if ((t & 63) == 0) { ss[0][w] = sp_; ss[1][w] = sn_; }
    __syncthreads();
    if (t == 0) {
        float SP = ss[0][0] + ss[0][1] + ss[0][2] + ss[0][3];
        float SN = ss[1][0] + ss[1][1] + ss[1][2] + ss[1][3];
        float x = (mp + logf(SP)) + (mn + logf(SN));
        atomicAdd(&acc[0], softplus_(x) * (1.f / 24.f));
    }
}

// ---------------- col logsumexp: phase 1 (partials) ----------------
__global__ __launch_bounds__(256) void k_col1(const float* __restrict__ Dm,
                                              const u8* __restrict__ gt,
                                              float* __restrict__ part) {
    const int t = threadIdx.x;
    const int cl = t & 63, rq = t >> 6;
    const int c = blockIdx.x * 64 + cl;
    const int r0 = blockIdx.y * 256;
    float mp = -INFINITY, sp_ = 0.f, mn = -INFINITY, sn_ = 0.f;
    for (int r = r0 + rq; r < r0 + 256; r += 4) {
        float d = Dm[(size_t)r * 2048 + c];
        bool g = gt[(size_t)r * 2048 + c] != 0;
        float lp, ln;
        circle_terms(d, g, lp, ln);
        float nm = fmaxf(mp, lp); sp_ = sp_ * expf(mp - nm) + expf(lp - nm); mp = nm;
        nm = fmaxf(mn, ln); sn_ = sn_ * expf(mn - nm) + expf(ln - nm); mn = nm;
    }
    __shared__ float red[4][64][4];
    red[rq][cl][0] = mp; red[rq][cl][1] = sp_; red[rq][cl][2] = mn; red[rq][cl][3] = sn_;
    __syncthreads();
    if (rq == 0) {
        float M = mp, S = sp_, Mn = mn, Sn = sn_;
        #pragma unroll
        for (int q = 1; q < 4; ++q) {
            float m2 = red[q][cl][0], s2 = red[q][cl][1];
            float nm = fmaxf(M, m2);
            S = S * expf(M - nm) + s2 * expf(m2 - nm); M = nm;
            m2 = red[q][cl][2]; s2 = red[q][cl][3];
            nm = fmaxf(Mn, m2);
            Sn = Sn * expf(Mn - nm) + s2 * expf(m2 - nm); Mn = nm;
        }
        float* p = part + ((size_t)blockIdx.y * 2048 + c) * 4;
        p[0] = M; p[1] = S; p[2] = Mn; p[3] = Sn;
    }
}

// ---------------- col logsumexp: phase 2 (merge + loss) ----------------
__global__ void k_col2(const float* __restrict__ part, float* __restrict__ acc) {
    int c = blockIdx.x * 256 + threadIdx.x;   // 0..2047
    float M = -INFINITY, S = 0.f, Mn = -INFINITY, Sn = 0.f;
    for (int q = 0; q < 8; ++q) {
        const float* p = part + ((size_t)q * 2048 + c) * 4;
        float m2 = p[0], s2 = p[1];
        float nm = fmaxf(M, m2);
        S = S * expf(M - nm) + s2 * expf(m2 - nm); M = nm;
        m2 = p[2]; s2 = p[3];
        nm = fmaxf(Mn, m2);
        Sn = Sn * expf(Mn - nm) + s2 * expf(m2 - nm); Mn = nm;
    }
    float x = (M + logf(S)) + (Mn + logf(Sn));
    float l = softplus_(x) * (1.f / 24.f);
    for (int o = 32; o; o >>= 1) l += __shfl_xor(l, o);
    __shared__ float wsum[4];
    if ((threadIdx.x & 63) == 0) wsum[threadIdx.x >> 6] = l;
    __syncthreads();
    if (threadIdx.x == 0) atomicAdd(&acc[1], wsum[0] + wsum[1] + wsum[2] + wsum[3]);
}

// ---------------- finalize ----------------
__global__ void k_fin(const float* __restrict__ acc, float* __restrict__ out) {
    float l1 = (acc[0] + acc[1]) * (0.5f / 2048.f);
    float l2 = acc[2] * (1.f / 4096.f);
    out[0] = l1 + l2; out[1] = l1; out[2] = l2;
}

extern "C" void kernel_launch(void* const* d_in, const int* in_sizes, int n_in,
                              void* d_out, int out_size, void* d_ws, size_t ws_size,
                              hipStream_t stream) {
    (void)in_sizes; (void)n_in; (void)out_size; (void)ws_size;
    const float* ref_points = (const float*)d_in[0];
    const float* src_points = (const float*)d_in[1];
    const float* ref_c      = (const float*)d_in[2];
    const float* src_c      = (const float*)d_in[3];
    const float* ref_f      = (const float*)d_in[4];
    const float* src_f      = (const float*)d_in[5];
    const int*   gti        = (const int*)d_in[6];
    const float* gtv        = (const float*)d_in[7];
    const float* spm        = (const float*)d_in[8];
    const int*   rbi        = (const int*)d_in[9];
    const int*   sbi        = (const int*)d_in[10];

    char* ws = (char*)d_ws;
    float* Dm   = (float*)(ws + OFF_D);
    u8*    gt   = (u8*)   (ws + OFF_GT);
    u64*   nn   = (u64*)  (ws + OFF_NN);
    u32*   bm   = (u32*)  (ws + OFF_BM);
    u8*    mask = (u8*)   (ws + OFF_MASK);
    u64*   cand = (u64*)  (ws + OFF_CAND);
    float* acc  = (float*)(ws + OFF_ACC);
    u32*   cnt  = (u32*)  (ws + OFF_CNT);
    float* part = (float*)(ws + OFF_PART);
    u64*   hash = (u64*)  (ws + OFF_HASH);

    k_init<<<1024, 256, 0, stream>>>(nn, bm, acc, hash, cnt, (uint4*)gt);
    k_bm  <<<(2*NBACK + 255)/256, 256, 0, stream>>>(rbi, sbi, bm);
    k_nn  <<<dim3(256, 2), 256, 0, stream>>>(ref_points, src_points, ref_c, src_c, nn);
    k_mask<<<16, 256, 0, stream>>>(nn, bm, spm, mask, acc);
    k_scat1<<<16, 256, 0, stream>>>(gti, mask, gt, hash);
    k_scat2<<<32, 256, 0, stream>>>(hash, gtv, mask, cand, cnt);
    k_top <<<1, 1024, 0, stream>>>(cand, cnt, gt);
    k_gemm<<<dim3(16, 16), 256, 0, stream>>>(ref_f, src_f, spm, Dm);
    k_row <<<2048, 256, 0, stream>>>(Dm, gt, acc);
    k_col1<<<dim3(32, 8), 256, 0, stream>>>(Dm, gt, part);
    k_col2<<<8, 256, 0, stream>>>(part, acc);
    k_fin <<<1, 1, 0, stream>>>(acc, (float*)d_out);
}

// Round 6
// 138.663 us; speedup vs baseline: 2.3117x; 1.2752x over previous
//
#include <hip/hip_runtime.h>
#include <math.h>

using u8  = unsigned char;
using u32 = unsigned int;
using u64 = unsigned long long;

typedef short short8 __attribute__((ext_vector_type(8)));
typedef float f32x4  __attribute__((ext_vector_type(4)));

#define MC 2048
#define NC 2048
#define DF 256
#define NFULL 50000
#define NBACK 30000
#define KCORR 4096
#define MAXPTS 256
#define NN_CHUNK 391   // 128 chunks * 391 = 50048 >= 50000

// ---------------- workspace layout ----------------
constexpr size_t OFF_ROWP = 0;                                // 64*2048 float4 = 2 MB
constexpr size_t OFF_COLP = (size_t)2 * 1024 * 1024;          // 32*2048 float4 = 1 MB
constexpr size_t OFF_GT   = (size_t)16 * 1024 * 1024;         // 2048*2048 u8 = 4 MB
constexpr size_t OFF_NN   = OFF_GT + (size_t)4 * 1024 * 1024; // 4096 u64
constexpr size_t BM_WORDS = 1568;                             // ceil(50000/32)+pad
constexpr size_t OFF_BM   = OFF_NN + 4096 * 8;                // 2*1568 u32
constexpr size_t OFF_MASK = OFF_BM + 2 * BM_WORDS * 4;        // 4096 u8
constexpr size_t OFF_CAND = OFF_MASK + 4096;                  // 4096 u64
constexpr size_t OFF_ACC  = OFF_CAND + 4096 * 8;              // 8 f32
constexpr size_t OFF_CNT  = OFF_ACC + 256;                    // 1 u32 (+pad)
constexpr size_t OFF_HASH = OFF_CNT + 256;                    // 8192 u64 = 64 KB

// ---------------- init (also zeroes gt: 1024 blocks x 256 thr x 16B = 4 MB) ----------------
__global__ __launch_bounds__(256) void k_init(u64* __restrict__ nn, u32* __restrict__ bm,
                       float* __restrict__ acc, u64* __restrict__ hash, u32* __restrict__ cnt,
                       uint4* __restrict__ gt4) {
    int e = blockIdx.x * 256 + threadIdx.x;   // 0..262143
    gt4[e] = make_uint4(0u, 0u, 0u, 0u);
    if (e < 8192) hash[e] = 0ull;
    if (e < 4096) nn[e] = ~0ull;
    if (e < (int)(2 * BM_WORDS)) bm[e] = 0u;
    if (e < 8) acc[e] = 0.f;
    if (e == 0) *cnt = 0u;
}

// ---------------- back-index bitmaps ----------------
__global__ void k_bm(const int* __restrict__ rb, const int* __restrict__ sb, u32* __restrict__ bm) {
    int e = blockIdx.x * 256 + threadIdx.x;
    if (e < NBACK) {
        int v = rb[e];
        atomicOr(&bm[v >> 5], 1u << (v & 31));
    } else if (e < 2*NBACK) {
        int v = sb[e - NBACK];
        atomicOr(&bm[BM_WORDS + (v >> 5)], 1u << (v & 31));
    }
}

// ---------------- NN argmin ----------------
// grid: x = (4 i-blocks) | (128 chunks << 2), y = side. block 256, IPT=2.
// 1024 blocks -> 4 blocks/CU -> 4 waves/SIMD (latency hiding).
__global__ __launch_bounds__(256) void k_nn(
        const float* __restrict__ fr, const float* __restrict__ fs,
        const float* __restrict__ cr, const float* __restrict__ cs,
        u64* __restrict__ nn) {
    const int side = blockIdx.y;
    const float* full = side ? fs : fr;
    const float* corr = side ? cs : cr;
    const int ib = blockIdx.x & 3, ch = blockIdx.x >> 2;
    const int t = threadIdx.x;

    __shared__ float4 s4[NN_CHUNK];
    const int j0 = ch * NN_CHUNK;
    for (int e = t; e < NN_CHUNK; e += 256) {
        int j = j0 + e;
        float4 v;
        if (j < NFULL) {
            float x = full[j*3], y = full[j*3+1], z = full[j*3+2];
            v = make_float4(x, y, z, x*x + y*y + z*z);
        } else {
            v = make_float4(0.f, 0.f, 0.f, 3.0e38f);   // sentinel: never wins
        }
        s4[e] = v;
    }

    float ax[2], ay[2], az[2], bd[2];
    u32 bj[2];
    #pragma unroll
    for (int q = 0; q < 2; ++q) {
        int i = ib * 512 + q * 256 + t;
        float cx = corr[i*3], cy = corr[i*3+1], cz = corr[i*3+2];
        ax[q] = -2.f*cx; ay[q] = -2.f*cy; az[q] = -2.f*cz;
        bd[q] = 3.4e38f; bj[q] = 0u;
    }
    __syncthreads();

    #pragma unroll 4
    for (int jj = 0; jj < NN_CHUNK; ++jj) {
        float4 p = s4[jj];
        #pragma unroll
        for (int q = 0; q < 2; ++q) {
            float d = fmaf(ax[q], p.x, fmaf(ay[q], p.y, fmaf(az[q], p.z, p.w)));
            if (d < bd[q]) { bd[q] = d; bj[q] = (u32)(j0 + jj); }
        }
    }

    #pragma unroll
    for (int q = 0; q < 2; ++q) {
        int i = ib * 512 + q * 256 + t;
        float cn = 0.25f * fmaf(ax[q], ax[q], fmaf(ay[q], ay[q], az[q]*az[q]));
        float bf = bd[q] + cn;
        u32 db = __float_as_uint(bf);
        db = (db & 0x80000000u) ? ~db : (db | 0x80000000u);
        atomicMin(&nn[side * 2048 + i], ((u64)db << 32) | bj[q]);
    }
}

// ---------------- masks + loss2 ----------------
__global__ void k_mask(const u64* __restrict__ nn, const u32* __restrict__ bm,
                       const float* __restrict__ spm, u8* __restrict__ mask,
                       float* __restrict__ acc) {
    int t = blockIdx.x * 256 + threadIdx.x;   // 0..4095
    int side = t >> 11;
    u32 j = (u32)(nn[t] & 0xFFFFFFFFull);
    u32 bit = (bm[side * BM_WORDS + (j >> 5)] >> (j & 31)) & 1u;
    mask[t] = (u8)bit;
    float c = fabsf((1.f - spm[t]) - (float)bit);
    for (int o = 32; o; o >>= 1) c += __shfl_xor(c, o);
    __shared__ float wsum[4];
    if ((threadIdx.x & 63) == 0) wsum[threadIdx.x >> 6] = c;
    __syncthreads();
    if (threadIdx.x == 0) atomicAdd(&acc[2], wsum[0] + wsum[1] + wsum[2] + wsum[3]);
}

// ---------------- scatter phase 1: gt set + last-wins dedup via hash ----------------
__global__ void k_scat1(const int* __restrict__ gti, const u8* __restrict__ mask,
                        u8* __restrict__ gt, u64* __restrict__ hash) {
    int k = blockIdx.x * 256 + threadIdx.x;   // 0..4095
    int xi = gti[2*k], yi = gti[2*k+1];
    u32 cell = (u32)(xi * 2048 + yi);
    if (mask[xi] && mask[2048 + yi]) gt[cell] = 1;
    u64 val = ((u64)(cell + 1) << 12) | (u32)k;
    u32 h = (cell * 2654435761u) >> 19;       // 13-bit hash -> 8192 slots
    while (true) {
        u64 cur = hash[h];
        if ((cur >> 12) == (u64)(cell + 1)) { atomicMax(&hash[h], val); return; }
        if (cur == 0ull) {
            u64 prev = atomicCAS(&hash[h], 0ull, val);
            if (prev == 0ull) return;
            if ((prev >> 12) == (u64)(cell + 1)) { atomicMax(&hash[h], val); return; }
        }
        h = (h + 1) & 8191;
    }
}

// ---------------- scatter phase 2: collect masked candidates ----------------
__global__ void k_scat2(const u64* __restrict__ hash, const float* __restrict__ gtv,
                        const u8* __restrict__ mask, u64* __restrict__ cand,
                        u32* __restrict__ cnt) {
    int e = blockIdx.x * 256 + threadIdx.x;   // 0..8191
    u64 s = hash[e];
    if (s == 0ull) return;
    u32 cell = (u32)(s >> 12) - 1u;
    int xi = cell >> 11, yi = cell & 2047;
    if (!(mask[xi] && mask[2048 + yi])) return;
    u32 k = (u32)(s & 0xFFFull);
    u32 vb = __float_as_uint(gtv[k]);         // overlaps >= 0 -> bits monotonic
    u32 idx = atomicAdd(cnt, 1u);
    cand[idx] = ((u64)vb << 22) | (u32)(0x3FFFFF - cell);
}

// ---------------- scatter phase 3: top-256 cap via O(n^2) rank ----------------
__global__ __launch_bounds__(1024) void k_top(const u64* __restrict__ cand,
                                              const u32* __restrict__ cnt,
                                              u8* __restrict__ gt) {
    __shared__ u64 keys[4096];
    const int n = (int)*cnt;
    if (n <= MAXPTS) return;
    const int t = threadIdx.x;
    for (int e = t; e < n; e += 1024) keys[e] = cand[e];
    __syncthreads();
    for (int c = t; c < n; c += 1024) {
        u64 me = keys[c];
        int rank = 0;
        for (int j = 0; j < n; ++j) rank += (keys[j] > me);
        if (rank >= MAXPTS) {
            u32 cell = 0x3FFFFFu - (u32)(me & 0x3FFFFFull);
            gt[cell] = 0;
        }
    }
}

// ---------------- circle-loss terms ----------------
__device__ __forceinline__ void circle_terms(float d, bool g, float& lp, float& ln) {
    if (g) { float a = d - 0.1f; lp = a > 0.f ? 24.f*a*a : 0.f; ln = 0.f; }
    else   { float b = 1.4f - d; ln = b > 0.f ? 24.f*b*b : 0.f; lp = 0.f; }
}

__device__ __forceinline__ float softplus_(float x) {
    return fmaxf(x, 0.f) + log1pf(expf(-fabsf(x)));
}

// ---------------- fused MFMA bf16 GEMM + laplace + row/col LSE partials ----------------
// Tile 128x64 (M x N), BK=128, grid (32 j-tiles, 16 i-tiles) = 512 blocks = 2/CU.
// 4 waves as 2x2; wave subtile 64x32 = 4x2 frags of 16x16x32.
// LDS fragment-major (frag = 1 KB of [q][r] 16B chunks): ds_read_b128 = frag_base
// + lane*16, linear, conflict-free. f32->bf16 by truncation (1 v_perm per pair;
// error budget ~1e-3 on d, threshold 2.7e-2).
// Epilogue: d in-register, gt bitmask, two-phase (max-bfly, sum-bfly) LSE ->
// row partials rowp[64][2048] (m,s)pos+(m,s)neg, col partials colp[32][2048].
__global__ __launch_bounds__(256) void k_gemm(
        const float* __restrict__ A, const float* __restrict__ B,
        const float* __restrict__ spm, const u8* __restrict__ gt,
        float4* __restrict__ rowp, float4* __restrict__ colp) {
    __shared__ __align__(16) short As[16384];   // 32 KB: 32 frags (8m x 4k)
    __shared__ __align__(16) short Bs[8192];    // 16 KB: 16 frags (4n x 4k)
    const int t = threadIdx.x;
    const int l = t & 63, wid = t >> 6;
    const int wm = wid >> 1, wn = wid & 1;
    const int i0 = blockIdx.y * 128, j0 = blockIdx.x * 64;

    f32x4 acc[4][2] = {};

    for (int ks = 0; ks < 2; ++ks) {
        __syncthreads();
        #pragma unroll
        for (int it = 0; it < 12; ++it) {
            int sl = it * 256 + t;                 // 0..3071 slots of 16B
            int c = sl & 63, q = c >> 4, r15 = c & 15;
            const float* src;
            short* dst;
            int kf;
            if (it < 8) {                          // A: slots 0..2047
                int frag = sl >> 6;                // mf(8) x kf(4)
                kf = frag & 3;
                int row = (frag >> 2) * 16 + r15;
                src = A + (size_t)(i0 + row) * 256;
                dst = &As[sl * 8];
            } else {                               // B: slots 2048..3071
                int sl2 = sl - 2048;
                int frag = sl2 >> 6;               // nf(4) x kf(4)
                kf = frag & 3;
                int row = (frag >> 2) * 16 + r15;
                src = B + (size_t)(j0 + row) * 256;
                dst = &Bs[sl2 * 8];
            }
            int col = ks * 128 + kf * 32 + q * 8;
            float4 v0 = *(const float4*)(src + col);
            float4 v1 = *(const float4*)(src + col + 4);
            u32 w0 = __builtin_amdgcn_perm(__float_as_uint(v0.y), __float_as_uint(v0.x), 0x07060302u);
            u32 w1 = __builtin_amdgcn_perm(__float_as_uint(v0.w), __float_as_uint(v0.z), 0x07060302u);
            u32 w2 = __builtin_amdgcn_perm(__float_as_uint(v1.y), __float_as_uint(v1.x), 0x07060302u);
            u32 w3 = __builtin_amdgcn_perm(__float_as_uint(v1.w), __float_as_uint(v1.z), 0x07060302u);
            *(uint4*)dst = make_uint4(w0, w1, w2, w3);
        }
        __syncthreads();

        #pragma unroll
        for (int kf = 0; kf < 4; ++kf) {
            short8 a[4], b[2];
            #pragma unroll
            for (int mi = 0; mi < 4; ++mi)
                a[mi] = *(const short8*)&As[(((wm*4 + mi)*4 + kf) << 9) + l*8];
            #pragma unroll
            for (int ni = 0; ni < 2; ++ni)
                b[ni] = *(const short8*)&Bs[(((wn*2 + ni)*4 + kf) << 9) + l*8];
            #pragma unroll
            for (int mi = 0; mi < 4; ++mi)
                #pragma unroll
                for (int ni = 0; ni < 2; ++ni)
                    acc[mi][ni] = __builtin_amdgcn_mfma_f32_16x16x32_bf16(
                        a[mi], b[ni], acc[mi][ni], 0, 0, 0);
        }
    }

    // ---- epilogue ----
    // C/D layout: col = lane&15, row = (lane>>4)*4 + reg  [m89-verified]
    const int cq = l >> 4, cr = l & 15;
    const int rows0 = i0 + wm * 64, cols0 = j0 + wn * 32;

    float vmj[2];
    #pragma unroll
    for (int ni = 0; ni < 2; ++ni) vmj[ni] = 1.f - spm[2048 + cols0 + ni*16 + cr];
    float vmi[4][4];
    #pragma unroll
    for (int mi = 0; mi < 4; ++mi)
        #pragma unroll
        for (int rr = 0; rr < 4; ++rr)
            vmi[mi][rr] = 1.f - spm[rows0 + mi*16 + cq*4 + rr];

    // d in place + gt bitmask (bit mi*8 + ni*4 + rr)
    u32 gmask = 0;
    #pragma unroll
    for (int mi = 0; mi < 4; ++mi)
        #pragma unroll
        for (int ni = 0; ni < 2; ++ni)
            #pragma unroll
            for (int rr = 0; rr < 4; ++rr) {
                int row = rows0 + mi*16 + cq*4 + rr;
                int col = cols0 + ni*16 + cr;
                float s  = acc[mi][ni][rr];
                float fs = fmaxf(2.f - 2.f*s, 0.f);
                float d  = sqrtf(fs) * expf(0.5f * vmi[mi][rr] * vmj[ni]);
                acc[mi][ni][rr] = d;
                if (gt[(size_t)row * 2048 + col])
                    gmask |= 1u << (mi*8 + ni*4 + rr);
            }

    const int jt2 = blockIdx.x * 2 + wn;   // 0..63
    const int it2 = blockIdx.y * 2 + wm;   // 0..31

    // row-LSE: per row (mi,cq,rr), over ni(2) x 16 lanes. two-phase.
    #pragma unroll
    for (int mi = 0; mi < 4; ++mi)
        #pragma unroll
        for (int rr = 0; rr < 4; ++rr) {
            float lp0, ln0, lp1, ln1;
            circle_terms(acc[mi][0][rr], (gmask >> (mi*8 + rr)) & 1, lp0, ln0);
            circle_terms(acc[mi][1][rr], (gmask >> (mi*8 + 4 + rr)) & 1, lp1, ln1);
            float mp = fmaxf(lp0, lp1), mn = fmaxf(ln0, ln1);
            #pragma unroll
            for (int o = 1; o < 16; o <<= 1) {
                mp = fmaxf(mp, __shfl_xor(mp, o));
                mn = fmaxf(mn, __shfl_xor(mn, o));
            }
            float sp = expf(lp0 - mp) + expf(lp1 - mp);
            float sn = expf(ln0 - mn) + expf(ln1 - mn);
            #pragma unroll
            for (int o = 1; o < 16; o <<= 1) {
                sp += __shfl_xor(sp, o);
                sn += __shfl_xor(sn, o);
            }
            if (cr == mi*4 + rr) {
                int row = rows0 + mi*16 + cq*4 + rr;
                rowp[(size_t)jt2 * 2048 + row] = make_float4(mp, sp, mn, sn);
            }
        }

    // col-LSE: per col (ni,cr), over mi(4) x rr(4) in-lane, then cq bfly.
    #pragma unroll
    for (int ni = 0; ni < 2; ++ni) {
        float lp[16], ln[16];
        #pragma unroll
        for (int mi = 0; mi < 4; ++mi)
            #pragma unroll
            for (int rr = 0; rr < 4; ++rr)
                circle_terms(acc[mi][ni][rr], (gmask >> (mi*8 + ni*4 + rr)) & 1,
                             lp[mi*4+rr], ln[mi*4+rr]);
        float mp = lp[0], mn = ln[0];
        #pragma unroll
        for (int e = 1; e < 16; ++e) { mp = fmaxf(mp, lp[e]); mn = fmaxf(mn, ln[e]); }
        #pragma unroll
        for (int o = 16; o < 64; o <<= 1) {
            mp = fmaxf(mp, __shfl_xor(mp, o));
            mn = fmaxf(mn, __shfl_xor(mn, o));
        }
        float sp = 0.f, sn = 0.f;
        #pragma unroll
        for (int e = 0; e < 16; ++e) { sp += expf(lp[e] - mp); sn += expf(ln[e] - mn); }
        #pragma unroll
        for (int o = 16; o < 64; o <<= 1) {
            sp += __shfl_xor(sp, o);
            sn += __shfl_xor(sn, o);
        }
        if (cq == 0) {
            int col = cols0 + ni*16 + cr;
            colp[(size_t)it2 * 2048 + col] = make_float4(mp, sp, mn, sn);
        }
    }
}

// ---------------- merge row partials (64 per row) -> loss_row sum ----------------
__global__ __launch_bounds__(256) void k_rowm(const float4* __restrict__ rowp,
                                              float* __restrict__ acc) {
    int row = blockIdx.x * 256 + threadIdx.x;   // 0..2047
    float Mp = -1e30f, Sp = 0.f, Mn = -1e30f, Sn = 0.f;
    for (int jt = 0; jt < 64; ++jt) {
        float4 p = rowp[(size_t)jt * 2048 + row];
        float nm = fmaxf(Mp, p.x); Sp = Sp*expf(Mp-nm) + p.y*expf(p.x-nm); Mp = nm;
        nm = fmaxf(Mn, p.z); Sn = Sn*expf(Mn-nm) + p.w*expf(p.z-nm); Mn = nm;
    }
    float x = (Mp + logf(Sp)) + (Mn + logf(Sn));
    float lv = softplus_(x) * (1.f / 24.f);
    for (int o = 32; o; o >>= 1) lv += __shfl_xor(lv, o);
    __shared__ float wsum[4];
    if ((threadIdx.x & 63) == 0) wsum[threadIdx.x >> 6] = lv;
    __syncthreads();
    if (threadIdx.x == 0) atomicAdd(&acc[0], wsum[0] + wsum[1] + wsum[2] + wsum[3]);
}

// ---------------- merge col partials (32 per col) -> loss_col sum ----------------
__global__ __launch_bounds__(256) void k_colm(const float4* __restrict__ colp,
                                              float* __restrict__ acc) {
    int col = blockIdx.x * 256 + threadIdx.x;   // 0..2047
    float Mp = -1e30f, Sp = 0.f, Mn = -1e30f, Sn = 0.f;
    for (int it = 0; it < 32; ++it) {
        float4 p = colp[(size_t)it * 2048 + col];
        float nm = fmaxf(Mp, p.x); Sp = Sp*expf(Mp-nm) + p.y*expf(p.x-nm); Mp = nm;
        nm = fmaxf(Mn, p.z); Sn = Sn*expf(Mn-nm) + p.w*expf(p.z-nm); Mn = nm;
    }
    float x = (Mp + logf(Sp)) + (Mn + logf(Sn));
    float lv = softplus_(x) * (1.f / 24.f);
    for (int o = 32; o; o >>= 1) lv += __shfl_xor(lv, o);
    __shared__ float wsum[4];
    if ((threadIdx.x & 63) == 0) wsum[threadIdx.x >> 6] = lv;
    __syncthreads();
    if (threadIdx.x == 0) atomicAdd(&acc[1], wsum[0] + wsum[1] + wsum[2] + wsum[3]);
}

// ---------------- finalize ----------------
__global__ void k_fin(const float* __restrict__ acc, float* __restrict__ out) {
    float l1 = (acc[0] + acc[1]) * (0.5f / 2048.f);
    float l2 = acc[2] * (1.f / 4096.f);
    out[0] = l1 + l2; out[1] = l1; out[2] = l2;
}

extern "C" void kernel_launch(void* const* d_in, const int* in_sizes, int n_in,
                              void* d_out, int out_size, void* d_ws, size_t ws_size,
                              hipStream_t stream) {
    (void)in_sizes; (void)n_in; (void)out_size; (void)ws_size;
    const float* ref_points = (const float*)d_in[0];
    const float* src_points = (const float*)d_in[1];
    const float* ref_c      = (const float*)d_in[2];
    const float* src_c      = (const float*)d_in[3];
    const float* ref_f      = (const float*)d_in[4];
    const float* src_f      = (const float*)d_in[5];
    const int*   gti        = (const int*)d_in[6];
    const float* gtv        = (const float*)d_in[7];
    const float* spm        = (const float*)d_in[8];
    const int*   rbi        = (const int*)d_in[9];
    const int*   sbi        = (const int*)d_in[10];

    char* ws = (char*)d_ws;
    float4* rowp = (float4*)(ws + OFF_ROWP);
    float4* colp = (float4*)(ws + OFF_COLP);
    u8*    gt   = (u8*)   (ws + OFF_GT);
    u64*   nn   = (u64*)  (ws + OFF_NN);
    u32*   bm   = (u32*)  (ws + OFF_BM);
    u8*    mask = (u8*)   (ws + OFF_MASK);
    u64*   cand = (u64*)  (ws + OFF_CAND);
    float* acc  = (float*)(ws + OFF_ACC);
    u32*   cnt  = (u32*)  (ws + OFF_CNT);
    u64*   hash = (u64*)  (ws + OFF_HASH);

    k_init<<<1024, 256, 0, stream>>>(nn, bm, acc, hash, cnt, (uint4*)gt);
    k_bm  <<<(2*NBACK + 255)/256, 256, 0, stream>>>(rbi, sbi, bm);
    k_nn  <<<dim3(512, 2), 256, 0, stream>>>(ref_points, src_points, ref_c, src_c, nn);
    k_mask<<<16, 256, 0, stream>>>(nn, bm, spm, mask, acc);
    k_scat1<<<16, 256, 0, stream>>>(gti, mask, gt, hash);
    k_scat2<<<32, 256, 0, stream>>>(hash, gtv, mask, cand, cnt);
    k_top <<<1, 1024, 0, stream>>>(cand, cnt, gt);
    k_gemm<<<dim3(32, 16), 256, 0, stream>>>(ref_f, src_f, spm, gt, rowp, colp);
    k_rowm<<<8, 256, 0, stream>>>(rowp, acc);
    k_colm<<<8, 256, 0, stream>>>(colp, acc);
    k_fin <<<1, 1, 0, stream>>>(acc, (float*)d_out);
}